// Round 1
// baseline (377.985 us; speedup 1.0000x reference)
//
#include <hip/hip_runtime.h>
#include <hip/hip_bf16.h>
#include <math.h>

#define S_LEN 2048
#define DMODEL 2048
#define NHEADS 16
#define HDIM 128

typedef __bf16 bf16x8 __attribute__((ext_vector_type(8)));
typedef float f32x4 __attribute__((ext_vector_type(4)));

__device__ __forceinline__ unsigned short f2b(float f) {
  union { float f; unsigned u; } c; c.f = f;
  unsigned r = (c.u + 0x7fffu + ((c.u >> 16) & 1u)) >> 16;
  return (unsigned short)r;
}
__device__ __forceinline__ float b2f(unsigned short b) {
  union { unsigned u; float f; } c; c.u = ((unsigned)b) << 16;
  return c.f;
}

__device__ __forceinline__ void gload_lds16(const unsigned short* g, unsigned short* l) {
  __builtin_amdgcn_global_load_lds(
      (__attribute__((address_space(1))) void*)(void*)g,
      (__attribute__((address_space(3))) void*)(void*)l, 16, 0, 0);
}

// ---------------- fp32 -> bf16 conversion ----------------
__global__ void cvt_f32_bf16_k(const float* __restrict__ in,
                               unsigned short* __restrict__ out, int n) {
  int i = (blockIdx.x * blockDim.x + threadIdx.x) * 4;
  if (i >= n) return;
  float4 v = *reinterpret_cast<const float4*>(in + i);
  ushort4 o;
  o.x = f2b(v.x); o.y = f2b(v.y); o.z = f2b(v.z); o.w = f2b(v.w);
  *reinterpret_cast<ushort4*>(out + i) = o;
}

// ---------------- RoPE cos/sin table (one-time, small) ----------------
__global__ void rope_table_k(float* __restrict__ cs, float* __restrict__ sn) {
  int idx = blockIdx.x * blockDim.x + threadIdx.x;  // S_LEN * 64
  int s = idx >> 6, i = idx & 63;
  float inv = powf(10000.0f, -(float)(2 * i) / 128.0f);
  float a = (float)s * inv;
  cs[idx] = cosf(a);
  sn[idx] = sinf(a);
}

// ---------------- RoPE apply (in-place on q,k bf16) ----------------
__global__ void rope_apply_k(unsigned short* __restrict__ q,
                             unsigned short* __restrict__ k,
                             const float* __restrict__ cs,
                             const float* __restrict__ sn) {
  int idx = blockIdx.x * blockDim.x + threadIdx.x;  // S*H*64
  int i = idx & 63;
  int h = (idx >> 6) & (NHEADS - 1);
  int s = idx >> 10;
  size_t base = (size_t)s * DMODEL + h * HDIM;
  float c = cs[s * 64 + i], sv = sn[s * 64 + i];
  float q1 = b2f(q[base + i]), q2 = b2f(q[base + i + 64]);
  q[base + i]      = f2b(q1 * c - q2 * sv);
  q[base + i + 64] = f2b(q2 * c + q1 * sv);
  float k1 = b2f(k[base + i]), k2 = b2f(k[base + i + 64]);
  k[base + i]      = f2b(k1 * c - k2 * sv);
  k[base + i + 64] = f2b(k2 * c + k1 * sv);
}

// ---------------- bf16 NT GEMM: C[m,n] = sum_k A[m,k]*B[n,k] ----------------
// 128x128 tile, BK=64, 4 waves (2x2), 16x16x32 MFMA, global_load_lds staging.
// blockIdx.z multiplexes up to 3 (B,C) pairs (fused QKV).
template <bool OUT_F32>
__global__ __launch_bounds__(256) void gemm_nt_k(
    const unsigned short* __restrict__ A, const unsigned short* __restrict__ B0,
    const unsigned short* __restrict__ B1, const unsigned short* __restrict__ B2,
    void* __restrict__ C0, void* __restrict__ C1, void* __restrict__ C2,
    int M, int N, int K) {
  __shared__ unsigned short As[128 * 64];
  __shared__ unsigned short Bs[128 * 64];

  const unsigned short* Bm = (blockIdx.z == 0) ? B0 : (blockIdx.z == 1) ? B1 : B2;
  void* Cout = (blockIdx.z == 0) ? C0 : (blockIdx.z == 1) ? C1 : C2;

  // XCD-aware swizzle (grid divisible by 8 here)
  int nwg = gridDim.x;
  int bid = blockIdx.x;
  int wg = ((nwg & 7) == 0) ? (bid & 7) * (nwg >> 3) + (bid >> 3) : bid;
  int ntile = N >> 7;
  int tm = wg / ntile, tn = wg % ntile;
  int m0 = tm << 7, n0 = tn << 7;

  int t = threadIdx.x;
  int wave = t >> 6, lane = t & 63;
  int g = lane >> 4, li = lane & 15;
  int wm = wave >> 1, wn = wave & 1;

  f32x4 acc[4][4];
#pragma unroll
  for (int i = 0; i < 4; ++i)
#pragma unroll
    for (int j = 0; j < 4; ++j) acc[i][j] = (f32x4){0.f, 0.f, 0.f, 0.f};

  for (int k0 = 0; k0 < K; k0 += 64) {
    __syncthreads();
#pragma unroll
    for (int i = 0; i < 4; ++i) {
      int cbase = i * 256 + wave * 64;
      int chunk = cbase + lane;
      int row = chunk >> 3, c8 = chunk & 7;
      gload_lds16(A + (size_t)(m0 + row) * K + k0 + c8 * 8, As + cbase * 8);
      gload_lds16(Bm + (size_t)(n0 + row) * K + k0 + c8 * 8, Bs + cbase * 8);
    }
    __syncthreads();
#pragma unroll
    for (int kk = 0; kk < 64; kk += 32) {
      bf16x8 a[4], b[4];
#pragma unroll
      for (int mi = 0; mi < 4; ++mi)
        a[mi] = *reinterpret_cast<const bf16x8*>(As + (wm * 64 + mi * 16 + li) * 64 + kk + g * 8);
#pragma unroll
      for (int ni = 0; ni < 4; ++ni)
        b[ni] = *reinterpret_cast<const bf16x8*>(Bs + (wn * 64 + ni * 16 + li) * 64 + kk + g * 8);
#pragma unroll
      for (int mi = 0; mi < 4; ++mi)
#pragma unroll
        for (int ni = 0; ni < 4; ++ni)
          acc[mi][ni] = __builtin_amdgcn_mfma_f32_16x16x32_bf16(a[mi], b[ni], acc[mi][ni], 0, 0, 0);
    }
  }

#pragma unroll
  for (int mi = 0; mi < 4; ++mi) {
#pragma unroll
    for (int ni = 0; ni < 4; ++ni) {
      int row = m0 + wm * 64 + mi * 16 + g * 4;
      int col = n0 + wn * 64 + ni * 16 + li;
#pragma unroll
      for (int r = 0; r < 4; ++r) {
        if (OUT_F32)
          reinterpret_cast<float*>(Cout)[(size_t)(row + r) * N + col] = acc[mi][ni][r];
        else
          reinterpret_cast<unsigned short*>(Cout)[(size_t)(row + r) * N + col] =
              f2b(acc[mi][ni][r]);
      }
    }
  }
}

// ---------------- causal flash attention ----------------
// grid (S/64, H), 256 threads (4 waves). Wave w owns 16 q-rows.
// K tile in XOR-swizzled LDS; V transposed into padded LDS; P via padded LDS.
__global__ __launch_bounds__(256) void flash_attn_k(
    const unsigned short* __restrict__ q, const unsigned short* __restrict__ k,
    const unsigned short* __restrict__ v, unsigned short* __restrict__ o) {
  __shared__ unsigned short Ks[64 * 128];   // swizzled: 16B chunk ^= (row&7)
  __shared__ unsigned short Vt[128 * 72];   // V^T, padded (+8)
  __shared__ unsigned short Ps[4 * 16 * 72];  // per-wave P, padded

  int qt = blockIdx.x, h = blockIdx.y;
  int t = threadIdx.x, wave = t >> 6, lane = t & 63;
  int g = lane >> 4, li = lane & 15;
  int q0 = qt * 64;
  int qrow = q0 + wave * 16 + li;

  // Q fragments in registers: A[i][d], i = li, d = kb*32 + g*8 + b
  bf16x8 qf[4];
#pragma unroll
  for (int kb = 0; kb < 4; ++kb)
    qf[kb] = *reinterpret_cast<const bf16x8*>(q + (size_t)qrow * DMODEL + h * HDIM + kb * 32 + g * 8);

  f32x4 O[8];
#pragma unroll
  for (int db = 0; db < 8; ++db) O[db] = (f32x4){0.f, 0.f, 0.f, 0.f};
  float m_r[4], l_r[4];
#pragma unroll
  for (int r = 0; r < 4; ++r) { m_r[r] = -1e30f; l_r[r] = 0.f; }

  const float sm = 0.08838834764831845f;  // 1/sqrt(128)
  const float L2E = 1.4426950408889634f;

  for (int kt = 0; kt <= qt; ++kt) {
    int kv0 = kt * 64;
    __syncthreads();
    // stage K (swizzled) + V^T (padded)
#pragma unroll
    for (int i = 0; i < 4; ++i) {
      int chunk = i * 256 + t;
      int row = chunk >> 4, c = chunk & 15;
      bf16x8 k8 = *reinterpret_cast<const bf16x8*>(k + (size_t)(kv0 + row) * DMODEL + h * HDIM + c * 8);
      *reinterpret_cast<bf16x8*>(Ks + row * 128 + ((c ^ (row & 7)) * 8)) = k8;
      bf16x8 v8 = *reinterpret_cast<const bf16x8*>(v + (size_t)(kv0 + row) * DMODEL + h * HDIM + c * 8);
      union { bf16x8 vec; unsigned short u[8]; } cv; cv.vec = v8;
#pragma unroll
      for (int j = 0; j < 8; ++j) Vt[(c * 8 + j) * 72 + row] = cv.u[j];
    }
    __syncthreads();

    // S = Q K^T  (per wave: 4 j-frags)
    f32x4 sf[4];
#pragma unroll
    for (int jb = 0; jb < 4; ++jb) sf[jb] = (f32x4){0.f, 0.f, 0.f, 0.f};
#pragma unroll
    for (int kb = 0; kb < 4; ++kb) {
#pragma unroll
      for (int jb = 0; jb < 4; ++jb) {
        int row = jb * 16 + li;
        int c = (kb * 4 + g) ^ (row & 7);
        bf16x8 kf = *reinterpret_cast<const bf16x8*>(Ks + row * 128 + c * 8);
        sf[jb] = __builtin_amdgcn_mfma_f32_16x16x32_bf16(qf[kb], kf, sf[jb], 0, 0, 0);
      }
    }

    // scale + causal mask + per-row max
    float sv[4][4];
    float pm[4] = {-1e30f, -1e30f, -1e30f, -1e30f};
#pragma unroll
    for (int jb = 0; jb < 4; ++jb) {
      int jcol = kv0 + jb * 16 + li;
#pragma unroll
      for (int r = 0; r < 4; ++r) {
        float x = sf[jb][r] * sm;
        int irow = q0 + wave * 16 + g * 4 + r;
        if (kt == qt && jcol > irow) x = -1e30f;
        sv[jb][r] = x;
        pm[r] = fmaxf(pm[r], x);
      }
    }
#pragma unroll
    for (int r = 0; r < 4; ++r) {
      float x = pm[r];
      x = fmaxf(x, __shfl_xor(x, 1));
      x = fmaxf(x, __shfl_xor(x, 2));
      x = fmaxf(x, __shfl_xor(x, 4));
      x = fmaxf(x, __shfl_xor(x, 8));
      pm[r] = x;
    }
    float alpha[4], ls[4];
#pragma unroll
    for (int r = 0; r < 4; ++r) {
      float nm = fmaxf(m_r[r], pm[r]);
      alpha[r] = exp2f((m_r[r] - nm) * L2E);
      m_r[r] = nm;
      ls[r] = 0.f;
    }
    // P = exp(S - m), write to per-wave LDS as bf16 (A-operand layout roundtrip)
#pragma unroll
    for (int jb = 0; jb < 4; ++jb) {
#pragma unroll
      for (int r = 0; r < 4; ++r) {
        float p = exp2f((sv[jb][r] - m_r[r]) * L2E);
        ls[r] += p;
        Ps[wave * 16 * 72 + (g * 4 + r) * 72 + jb * 16 + li] = f2b(p);
      }
    }
#pragma unroll
    for (int r = 0; r < 4; ++r) {
      float x = ls[r];
      x += __shfl_xor(x, 1);
      x += __shfl_xor(x, 2);
      x += __shfl_xor(x, 4);
      x += __shfl_xor(x, 8);
      l_r[r] = l_r[r] * alpha[r] + x;
    }
#pragma unroll
    for (int db = 0; db < 8; ++db)
#pragma unroll
      for (int r = 0; r < 4; ++r) O[db][r] *= alpha[r];

    // O += P V
#pragma unroll
    for (int ks = 0; ks < 2; ++ks) {
      bf16x8 pa = *reinterpret_cast<const bf16x8*>(Ps + wave * 16 * 72 + li * 72 + ks * 32 + g * 8);
#pragma unroll
      for (int db = 0; db < 8; ++db) {
        bf16x8 vbf = *reinterpret_cast<const bf16x8*>(Vt + (db * 16 + li) * 72 + ks * 32 + g * 8);
        O[db] = __builtin_amdgcn_mfma_f32_16x16x32_bf16(pa, vbf, O[db], 0, 0, 0);
      }
    }
  }

  // epilogue: O / l
#pragma unroll
  for (int db = 0; db < 8; ++db) {
#pragma unroll
    for (int r = 0; r < 4; ++r) {
      int row = q0 + wave * 16 + g * 4 + r;
      o[(size_t)row * DMODEL + h * HDIM + db * 16 + li] = f2b(O[db][r] / l_r[r]);
    }
  }
}

extern "C" void kernel_launch(void* const* d_in, const int* in_sizes, int n_in,
                              void* d_out, int out_size, void* d_ws, size_t ws_size,
                              hipStream_t stream) {
  const float* hs = (const float*)d_in[0];
  const float* Wq = (const float*)d_in[1];
  const float* Wk = (const float*)d_in[2];
  const float* Wv = (const float*)d_in[3];
  const float* Wo = (const float*)d_in[4];

  char* ws = (char*)d_ws;
  const size_t MB = 1024 * 1024;
  unsigned short* hs_b = (unsigned short*)(ws + 0 * MB);
  unsigned short* Wq_b = (unsigned short*)(ws + 8 * MB);
  unsigned short* Wk_b = (unsigned short*)(ws + 16 * MB);
  unsigned short* Wv_b = (unsigned short*)(ws + 24 * MB);
  unsigned short* Wo_b = (unsigned short*)(ws + 32 * MB);
  unsigned short* qb = (unsigned short*)(ws + 40 * MB);
  unsigned short* kb = (unsigned short*)(ws + 48 * MB);
  unsigned short* vb = (unsigned short*)(ws + 56 * MB);
  unsigned short* ab = (unsigned short*)(ws + 64 * MB);
  float* cs = (float*)(ws + 72 * MB);
  float* sn = (float*)(ws + 72 * MB + 512 * 1024);

  int n = S_LEN * DMODEL;  // 4M elements for each 2048x2048 tensor
  cvt_f32_bf16_k<<<n / 1024, 256, 0, stream>>>(hs, hs_b, n);
  cvt_f32_bf16_k<<<n / 1024, 256, 0, stream>>>(Wq, Wq_b, n);
  cvt_f32_bf16_k<<<n / 1024, 256, 0, stream>>>(Wk, Wk_b, n);
  cvt_f32_bf16_k<<<n / 1024, 256, 0, stream>>>(Wv, Wv_b, n);
  cvt_f32_bf16_k<<<n / 1024, 256, 0, stream>>>(Wo, Wo_b, n);

  rope_table_k<<<(S_LEN * 64) / 256, 256, 0, stream>>>(cs, sn);

  // fused QKV projection: 3 GEMMs in one launch (768 blocks)
  gemm_nt_k<false><<<dim3(256, 1, 3), 256, 0, stream>>>(
      hs_b, Wq_b, Wk_b, Wv_b, qb, kb, vb, 2048, 2048, 2048);

  rope_apply_k<<<(S_LEN * NHEADS * 64) / 256, 256, 0, stream>>>(qb, kb, cs, sn);

  flash_attn_k<<<dim3(S_LEN / 64, NHEADS), 256, 0, stream>>>(qb, kb, vb, ab);

  // output projection -> fp32 d_out
  gemm_nt_k<true><<<dim3(256, 1, 1), 256, 0, stream>>>(
      ab, Wo_b, Wo_b, Wo_b, d_out, d_out, d_out, 2048, 2048, 2048);
}

// Round 2
// 260.046 us; speedup vs baseline: 1.4535x; 1.4535x over previous
//
#include <hip/hip_runtime.h>
#include <hip/hip_bf16.h>
#include <math.h>

#define S_LEN 2048
#define DMODEL 2048
#define NHEADS 16
#define HDIM 128

typedef __bf16 bf16x8 __attribute__((ext_vector_type(8)));
typedef float f32x4 __attribute__((ext_vector_type(4)));

__device__ __forceinline__ unsigned short f2b(float f) {
  union { float f; unsigned u; } c; c.f = f;
  unsigned r = (c.u + 0x7fffu + ((c.u >> 16) & 1u)) >> 16;
  return (unsigned short)r;
}
__device__ __forceinline__ float b2f(unsigned short b) {
  union { unsigned u; float f; } c; c.u = ((unsigned)b) << 16;
  return c.f;
}

__device__ __forceinline__ void gload_lds16(const unsigned short* g, unsigned short* l) {
  __builtin_amdgcn_global_load_lds(
      (__attribute__((address_space(1))) void*)(void*)g,
      (__attribute__((address_space(3))) void*)(void*)l, 16, 0, 0);
}

// ---------------- fp32 -> bf16 conversion ----------------
__global__ void cvt_f32_bf16_k(const float* __restrict__ in,
                               unsigned short* __restrict__ out, int n) {
  int i = (blockIdx.x * blockDim.x + threadIdx.x) * 4;
  if (i >= n) return;
  float4 v = *reinterpret_cast<const float4*>(in + i);
  ushort4 o;
  o.x = f2b(v.x); o.y = f2b(v.y); o.z = f2b(v.z); o.w = f2b(v.w);
  *reinterpret_cast<ushort4*>(out + i) = o;
}

// ---------------- RoPE cos/sin table (one-time, small) ----------------
__global__ void rope_table_k(float* __restrict__ cs, float* __restrict__ sn) {
  int idx = blockIdx.x * blockDim.x + threadIdx.x;  // S_LEN * 64
  int s = idx >> 6, i = idx & 63;
  float inv = powf(10000.0f, -(float)(2 * i) / 128.0f);
  float a = (float)s * inv;
  cs[idx] = cosf(a);
  sn[idx] = sinf(a);
}

// ---------------- RoPE apply (in-place on q,k bf16) ----------------
__global__ void rope_apply_k(unsigned short* __restrict__ q,
                             unsigned short* __restrict__ k,
                             const float* __restrict__ cs,
                             const float* __restrict__ sn) {
  int idx = blockIdx.x * blockDim.x + threadIdx.x;  // S*H*64
  int i = idx & 63;
  int h = (idx >> 6) & (NHEADS - 1);
  int s = idx >> 10;
  size_t base = (size_t)s * DMODEL + h * HDIM;
  float c = cs[s * 64 + i], sv = sn[s * 64 + i];
  float q1 = b2f(q[base + i]), q2 = b2f(q[base + i + 64]);
  q[base + i]      = f2b(q1 * c - q2 * sv);
  q[base + i + 64] = f2b(q2 * c + q1 * sv);
  float k1 = b2f(k[base + i]), k2 = b2f(k[base + i + 64]);
  k[base + i]      = f2b(k1 * c - k2 * sv);
  k[base + i + 64] = f2b(k2 * c + k1 * sv);
}

// ---------------- bf16 2048x2048 transpose: out[c][r] = in[r][c] ----------------
__global__ __launch_bounds__(256) void transpose_bf16_k(
    const unsigned short* __restrict__ in, unsigned short* __restrict__ out) {
  __shared__ unsigned short tile[64][72];  // 144B row stride: 16B-aligned vec writes
  int bx = blockIdx.x, by = blockIdx.y;
  int t = threadIdx.x;
#pragma unroll
  for (int i = 0; i < 2; ++i) {
    int ch = i * 256 + t;
    int r = ch >> 3, c8 = ch & 7;
    bf16x8 v = *reinterpret_cast<const bf16x8*>(
        in + (size_t)(by * 64 + r) * DMODEL + bx * 64 + c8 * 8);
    *reinterpret_cast<bf16x8*>(&tile[r][c8 * 8]) = v;
  }
  __syncthreads();
#pragma unroll
  for (int i = 0; i < 2; ++i) {
    int ch = i * 256 + t;
    int c = ch >> 3, r8 = ch & 7;
    union { bf16x8 v; unsigned short u[8]; } w;
#pragma unroll
    for (int j = 0; j < 8; ++j) w.u[j] = tile[r8 * 8 + j][c];
    *reinterpret_cast<bf16x8*>(
        out + (size_t)(bx * 64 + c) * S_LEN + by * 64 + r8 * 8) = w.v;
  }
}

// ---------------- bf16 NT GEMM: C[m,n] = sum_k A[m,k]*B[n,k] ----------------
template <bool OUT_F32>
__global__ __launch_bounds__(256) void gemm_nt_k(
    const unsigned short* __restrict__ A, const unsigned short* __restrict__ B0,
    const unsigned short* __restrict__ B1, const unsigned short* __restrict__ B2,
    void* __restrict__ C0, void* __restrict__ C1, void* __restrict__ C2,
    int M, int N, int K) {
  __shared__ unsigned short As[128 * 64];
  __shared__ unsigned short Bs[128 * 64];

  const unsigned short* Bm = (blockIdx.z == 0) ? B0 : (blockIdx.z == 1) ? B1 : B2;
  void* Cout = (blockIdx.z == 0) ? C0 : (blockIdx.z == 1) ? C1 : C2;

  int nwg = gridDim.x;
  int bid = blockIdx.x;
  int wg = ((nwg & 7) == 0) ? (bid & 7) * (nwg >> 3) + (bid >> 3) : bid;
  int ntile = N >> 7;
  int tm = wg / ntile, tn = wg % ntile;
  int m0 = tm << 7, n0 = tn << 7;

  int t = threadIdx.x;
  int wave = t >> 6, lane = t & 63;
  int g = lane >> 4, li = lane & 15;
  int wm = wave >> 1, wn = wave & 1;

  f32x4 acc[4][4];
#pragma unroll
  for (int i = 0; i < 4; ++i)
#pragma unroll
    for (int j = 0; j < 4; ++j) acc[i][j] = (f32x4){0.f, 0.f, 0.f, 0.f};

  for (int k0 = 0; k0 < K; k0 += 64) {
    __syncthreads();
#pragma unroll
    for (int i = 0; i < 4; ++i) {
      int cbase = i * 256 + wave * 64;
      int chunk = cbase + lane;
      int row = chunk >> 3, c8 = chunk & 7;
      gload_lds16(A + (size_t)(m0 + row) * K + k0 + c8 * 8, As + cbase * 8);
      gload_lds16(Bm + (size_t)(n0 + row) * K + k0 + c8 * 8, Bs + cbase * 8);
    }
    __syncthreads();
#pragma unroll
    for (int kk = 0; kk < 64; kk += 32) {
      bf16x8 a[4], b[4];
#pragma unroll
      for (int mi = 0; mi < 4; ++mi)
        a[mi] = *reinterpret_cast<const bf16x8*>(As + (wm * 64 + mi * 16 + li) * 64 + kk + g * 8);
#pragma unroll
      for (int ni = 0; ni < 4; ++ni)
        b[ni] = *reinterpret_cast<const bf16x8*>(Bs + (wn * 64 + ni * 16 + li) * 64 + kk + g * 8);
#pragma unroll
      for (int mi = 0; mi < 4; ++mi)
#pragma unroll
        for (int ni = 0; ni < 4; ++ni)
          acc[mi][ni] = __builtin_amdgcn_mfma_f32_16x16x32_bf16(a[mi], b[ni], acc[mi][ni], 0, 0, 0);
    }
  }

#pragma unroll
  for (int mi = 0; mi < 4; ++mi) {
#pragma unroll
    for (int ni = 0; ni < 4; ++ni) {
      int row = m0 + wm * 64 + mi * 16 + g * 4;
      int col = n0 + wn * 64 + ni * 16 + li;
#pragma unroll
      for (int r = 0; r < 4; ++r) {
        if (OUT_F32)
          reinterpret_cast<float*>(Cout)[(size_t)(row + r) * N + col] = acc[mi][ni][r];
        else
          reinterpret_cast<unsigned short*>(Cout)[(size_t)(row + r) * N + col] =
              f2b(acc[mi][ni][r]);
      }
    }
  }
}

// ---------------- causal flash attention, v2 ----------------
// grid (16 pairs, 16 heads), 256 threads (4 waves, 16 q-rows each).
// Pair p processes q-tiles {p, 31-p}: exactly 33 tile-iters per block (balanced).
// K + V^T staged via global_load_lds with pre-swizzled source (rule #21),
// double-buffered, counted vmcnt(8) + raw barriers (T3/T4 minimum recipe).
__global__ __launch_bounds__(256) void flash_attn_k(
    const unsigned short* __restrict__ q, const unsigned short* __restrict__ k,
    const unsigned short* __restrict__ vt, unsigned short* __restrict__ o) {
  __shared__ unsigned short Ks[2][64 * 128];  // [kv row][d], chunk ^= row&7
  __shared__ unsigned short Vs[2][128 * 64];  // [d][kv row], chunk ^= row&7
  __shared__ unsigned short Ps[4 * 16 * 72];  // per-wave P roundtrip

  int p = blockIdx.x, h = blockIdx.y;
  int t = threadIdx.x, wave = t >> 6, lane = t & 63;
  int g = lane >> 4, li = lane & 15;

  const unsigned short* vth = vt + (size_t)h * HDIM * S_LEN;
  const float sm = 0.08838834764831845f;  // 1/sqrt(128)
  const float L2E = 1.4426950408889634f;

  auto stage = [&](int buf, int kt) {
    int kv0 = kt * 64;
#pragma unroll
    for (int i = 0; i < 4; ++i) {  // K tile: 64 rows x 16 chunks
      int ch = i * 256 + t;
      int row = ch >> 4, c = ch & 15;
      int cs_ = c ^ (row & 7);
      gload_lds16(k + (size_t)(kv0 + row) * DMODEL + h * HDIM + cs_ * 8,
                  &Ks[buf][ch * 8]);
    }
#pragma unroll
    for (int i = 0; i < 4; ++i) {  // V^T tile: 128 rows x 8 chunks
      int ch = i * 256 + t;
      int row = ch >> 3, c = ch & 7;
      int cs_ = c ^ (row & 7);
      gload_lds16(vth + (size_t)row * S_LEN + kv0 + cs_ * 8,
                  &Vs[buf][ch * 8]);
    }
  };

  for (int seg = 0; seg < 2; ++seg) {
    int qt = seg ? (31 - p) : p;
    int nIter = qt + 1;
    int q0 = qt * 64;
    int qrow = q0 + wave * 16 + li;

    bf16x8 qf[4];
#pragma unroll
    for (int kb = 0; kb < 4; ++kb)
      qf[kb] = *reinterpret_cast<const bf16x8*>(
          q + (size_t)qrow * DMODEL + h * HDIM + kb * 32 + g * 8);

    f32x4 O[8];
#pragma unroll
    for (int db = 0; db < 8; ++db) O[db] = (f32x4){0.f, 0.f, 0.f, 0.f};
    float m_r[4], l_r[4];
#pragma unroll
    for (int r = 0; r < 4; ++r) { m_r[r] = -1e30f; l_r[r] = 0.f; }

    stage(0, 0);  // prologue

    for (int it = 0; it < nIter; ++it) {
      int cur = it & 1;
      int kv0 = it * 64;
      if (it + 1 < nIter) {
        stage(cur ^ 1, it + 1);
        asm volatile("s_waitcnt vmcnt(8)" ::: "memory");
      } else {
        asm volatile("s_waitcnt vmcnt(0)" ::: "memory");
      }
      __builtin_amdgcn_s_barrier();
      asm volatile("" ::: "memory");

      // S = Q K^T
      f32x4 sf[4];
#pragma unroll
      for (int jb = 0; jb < 4; ++jb) sf[jb] = (f32x4){0.f, 0.f, 0.f, 0.f};
#pragma unroll
      for (int kb = 0; kb < 4; ++kb) {
#pragma unroll
        for (int jb = 0; jb < 4; ++jb) {
          int row = jb * 16 + li;
          int c = (kb * 4 + g) ^ (row & 7);
          bf16x8 kf = *reinterpret_cast<const bf16x8*>(&Ks[cur][row * 128 + c * 8]);
          sf[jb] = __builtin_amdgcn_mfma_f32_16x16x32_bf16(qf[kb], kf, sf[jb], 0, 0, 0);
        }
      }

      // scale + causal mask + per-row max
      float sv[4][4];
      float pm[4] = {-1e30f, -1e30f, -1e30f, -1e30f};
#pragma unroll
      for (int jb = 0; jb < 4; ++jb) {
        int jcol = kv0 + jb * 16 + li;
#pragma unroll
        for (int r = 0; r < 4; ++r) {
          float x = sf[jb][r] * sm;
          int irow = q0 + wave * 16 + g * 4 + r;
          if (it == qt && jcol > irow) x = -1e30f;
          sv[jb][r] = x;
          pm[r] = fmaxf(pm[r], x);
        }
      }
#pragma unroll
      for (int r = 0; r < 4; ++r) {
        float x = pm[r];
        x = fmaxf(x, __shfl_xor(x, 1));
        x = fmaxf(x, __shfl_xor(x, 2));
        x = fmaxf(x, __shfl_xor(x, 4));
        x = fmaxf(x, __shfl_xor(x, 8));
        pm[r] = x;
      }
      float alpha[4], ls[4];
#pragma unroll
      for (int r = 0; r < 4; ++r) {
        float nm = fmaxf(m_r[r], pm[r]);
        alpha[r] = exp2f((m_r[r] - nm) * L2E);
        m_r[r] = nm;
        ls[r] = 0.f;
      }
#pragma unroll
      for (int jb = 0; jb < 4; ++jb) {
#pragma unroll
        for (int r = 0; r < 4; ++r) {
          float pv = exp2f((sv[jb][r] - m_r[r]) * L2E);
          ls[r] += pv;
          Ps[wave * 16 * 72 + (g * 4 + r) * 72 + jb * 16 + li] = f2b(pv);
        }
      }
#pragma unroll
      for (int r = 0; r < 4; ++r) {
        float x = ls[r];
        x += __shfl_xor(x, 1);
        x += __shfl_xor(x, 2);
        x += __shfl_xor(x, 4);
        x += __shfl_xor(x, 8);
        l_r[r] = l_r[r] * alpha[r] + x;
      }
#pragma unroll
      for (int db = 0; db < 8; ++db)
#pragma unroll
        for (int r = 0; r < 4; ++r) O[db][r] *= alpha[r];

      // O += P V  (V^T tile as B-operand, swizzled read)
#pragma unroll
      for (int ks = 0; ks < 2; ++ks) {
        bf16x8 pa = *reinterpret_cast<const bf16x8*>(
            Ps + wave * 16 * 72 + li * 72 + ks * 32 + g * 8);
#pragma unroll
        for (int db = 0; db < 8; ++db) {
          int row = db * 16 + li;
          int c = (ks * 4 + g) ^ (row & 7);
          bf16x8 vbf = *reinterpret_cast<const bf16x8*>(&Vs[cur][row * 64 + c * 8]);
          O[db] = __builtin_amdgcn_mfma_f32_16x16x32_bf16(pa, vbf, O[db], 0, 0, 0);
        }
      }
      __builtin_amdgcn_s_barrier();
      asm volatile("" ::: "memory");
    }

    // epilogue: O / l
#pragma unroll
    for (int db = 0; db < 8; ++db) {
#pragma unroll
      for (int r = 0; r < 4; ++r) {
        int row = q0 + wave * 16 + g * 4 + r;
        o[(size_t)row * DMODEL + h * HDIM + db * 16 + li] = f2b(O[db][r] / l_r[r]);
      }
    }
  }
}

extern "C" void kernel_launch(void* const* d_in, const int* in_sizes, int n_in,
                              void* d_out, int out_size, void* d_ws, size_t ws_size,
                              hipStream_t stream) {
  const float* hs = (const float*)d_in[0];
  const float* Wq = (const float*)d_in[1];
  const float* Wk = (const float*)d_in[2];
  const float* Wv = (const float*)d_in[3];
  const float* Wo = (const float*)d_in[4];

  char* ws = (char*)d_ws;
  const size_t MB = 1024 * 1024;
  unsigned short* hs_b = (unsigned short*)(ws + 0 * MB);  // reused as vt after QKV GEMM
  unsigned short* Wq_b = (unsigned short*)(ws + 8 * MB);
  unsigned short* Wk_b = (unsigned short*)(ws + 16 * MB);
  unsigned short* Wv_b = (unsigned short*)(ws + 24 * MB);
  unsigned short* Wo_b = (unsigned short*)(ws + 32 * MB);
  unsigned short* qb = (unsigned short*)(ws + 40 * MB);
  unsigned short* kb = (unsigned short*)(ws + 48 * MB);
  unsigned short* vb = (unsigned short*)(ws + 56 * MB);
  unsigned short* ab = (unsigned short*)(ws + 64 * MB);
  float* cs = (float*)(ws + 72 * MB);
  float* sn = (float*)(ws + 72 * MB + 512 * 1024);
  unsigned short* vtb = hs_b;  // V^T [h][d][s]; hs_b is dead after the QKV GEMM

  int n = S_LEN * DMODEL;
  cvt_f32_bf16_k<<<n / 1024, 256, 0, stream>>>(hs, hs_b, n);
  cvt_f32_bf16_k<<<n / 1024, 256, 0, stream>>>(Wq, Wq_b, n);
  cvt_f32_bf16_k<<<n / 1024, 256, 0, stream>>>(Wk, Wk_b, n);
  cvt_f32_bf16_k<<<n / 1024, 256, 0, stream>>>(Wv, Wv_b, n);
  cvt_f32_bf16_k<<<n / 1024, 256, 0, stream>>>(Wo, Wo_b, n);

  rope_table_k<<<(S_LEN * 64) / 256, 256, 0, stream>>>(cs, sn);

  // fused QKV projection
  gemm_nt_k<false><<<dim3(256, 1, 3), 256, 0, stream>>>(
      hs_b, Wq_b, Wk_b, Wv_b, qb, kb, vb, 2048, 2048, 2048);

  // V -> V^T (per-head [d][s] layout == full 2048x2048 transpose)
  transpose_bf16_k<<<dim3(32, 32), 256, 0, stream>>>(vb, vtb);

  rope_apply_k<<<(S_LEN * NHEADS * 64) / 256, 256, 0, stream>>>(qb, kb, cs, sn);

  flash_attn_k<<<dim3(16, NHEADS), 256, 0, stream>>>(qb, kb, vtb, ab);

  // output projection -> fp32 d_out
  gemm_nt_k<true><<<dim3(256, 1, 1), 256, 0, stream>>>(
      ab, Wo_b, Wo_b, Wo_b, d_out, d_out, d_out, 2048, 2048, 2048);
}

// Round 4
// 236.381 us; speedup vs baseline: 1.5991x; 1.1001x over previous
//
#include <hip/hip_runtime.h>
#include <hip/hip_bf16.h>
#include <math.h>

#define S_LEN 2048
#define DMODEL 2048
#define NHEADS 16
#define HDIM 128

typedef __bf16 bf16x8 __attribute__((ext_vector_type(8)));
typedef float f32x4 __attribute__((ext_vector_type(4)));

__device__ __forceinline__ unsigned short f2b(float f) {
  union { float f; unsigned u; } c; c.f = f;
  unsigned r = (c.u + 0x7fffu + ((c.u >> 16) & 1u)) >> 16;
  return (unsigned short)r;
}
__device__ __forceinline__ float b2f(unsigned short b) {
  union { unsigned u; float f; } c; c.u = ((unsigned)b) << 16;
  return c.f;
}

__device__ __forceinline__ void gload_lds16(const unsigned short* g, unsigned short* l) {
  __builtin_amdgcn_global_load_lds(
      (__attribute__((address_space(1))) void*)(void*)g,
      (__attribute__((address_space(3))) void*)(void*)l, 16, 0, 0);
}

// ---------------- fp32 -> bf16 conversion ----------------
__global__ void cvt_f32_bf16_k(const float* __restrict__ in,
                               unsigned short* __restrict__ out, int n) {
  int i = (blockIdx.x * blockDim.x + threadIdx.x) * 4;
  if (i >= n) return;
  float4 v = *reinterpret_cast<const float4*>(in + i);
  ushort4 o;
  o.x = f2b(v.x); o.y = f2b(v.y); o.z = f2b(v.z); o.w = f2b(v.w);
  *reinterpret_cast<ushort4*>(out + i) = o;
}

// ---------------- RoPE cos/sin table ----------------
__global__ void rope_table_k(float* __restrict__ cs, float* __restrict__ sn) {
  int idx = blockIdx.x * blockDim.x + threadIdx.x;  // S_LEN * 64
  int s = idx >> 6, i = idx & 63;
  float inv = powf(10000.0f, -(float)(2 * i) / 128.0f);
  float a = (float)s * inv;
  cs[idx] = cosf(a);
  sn[idx] = sinf(a);
}

// ---------------- RoPE apply (in-place on q,k bf16) ----------------
__global__ void rope_apply_k(unsigned short* __restrict__ q,
                             unsigned short* __restrict__ k,
                             const float* __restrict__ cs,
                             const float* __restrict__ sn) {
  int idx = blockIdx.x * blockDim.x + threadIdx.x;  // S*H*64
  int i = idx & 63;
  int h = (idx >> 6) & (NHEADS - 1);
  int s = idx >> 10;
  size_t base = (size_t)s * DMODEL + h * HDIM;
  float c = cs[s * 64 + i], sv = sn[s * 64 + i];
  float q1 = b2f(q[base + i]), q2 = b2f(q[base + i + 64]);
  q[base + i]      = f2b(q1 * c - q2 * sv);
  q[base + i + 64] = f2b(q2 * c + q1 * sv);
  float k1 = b2f(k[base + i]), k2 = b2f(k[base + i + 64]);
  k[base + i]      = f2b(k1 * c - k2 * sv);
  k[base + i + 64] = f2b(k2 * c + k1 * sv);
}

// ---------------- bf16 2048x2048 transpose ----------------
__global__ __launch_bounds__(256) void transpose_bf16_k(
    const unsigned short* __restrict__ in, unsigned short* __restrict__ out) {
  __shared__ unsigned short tile[64][72];
  int bx = blockIdx.x, by = blockIdx.y;
  int t = threadIdx.x;
#pragma unroll
  for (int i = 0; i < 2; ++i) {
    int ch = i * 256 + t;
    int r = ch >> 3, c8 = ch & 7;
    bf16x8 v = *reinterpret_cast<const bf16x8*>(
        in + (size_t)(by * 64 + r) * DMODEL + bx * 64 + c8 * 8);
    *reinterpret_cast<bf16x8*>(&tile[r][c8 * 8]) = v;
  }
  __syncthreads();
#pragma unroll
  for (int i = 0; i < 2; ++i) {
    int ch = i * 256 + t;
    int c = ch >> 3, r8 = ch & 7;
    union { bf16x8 v; unsigned short u[8]; } w;
#pragma unroll
    for (int j = 0; j < 8; ++j) w.u[j] = tile[r8 * 8 + j][c];
    *reinterpret_cast<bf16x8*>(
        out + (size_t)(bx * 64 + c) * S_LEN + by * 64 + r8 * 8) = w.v;
  }
}

// ============ 8-phase 256-wide NT GEMM (m201-style, plain HIP) ============
// BM x 256 tile, BK=64, 512 threads (8 waves 2Mx4N), per-wave (BM/2) x 64.
// Region read schedule per K-tile: ph1 {Aq0, Bq0}, ph2 {Bq1}, ph3 {Aq1}.
// Region STAGE schedule (into buf[t&1], for tile t+2) is one phase AFTER the
// region's last read (WAR-safe: previous ENDBAR happens-before the DMA issue):
// ph2 {Aq0, Bq0}, ph3 {Bq1}, ph4 {Aq1}. vmcnt(8|6) once per K-tile at ph4.
// LDS XOR swizzle both-sides (rule #21): chunk c of row r lives at c^(r&7).

#define MIDBAR_SEQ()                                      \
  do {                                                    \
    asm volatile("" ::: "memory");                        \
    __builtin_amdgcn_s_barrier();                         \
    asm volatile("s_waitcnt lgkmcnt(0)" ::: "memory");    \
    __builtin_amdgcn_sched_barrier(0);                    \
    __builtin_amdgcn_s_setprio(1);                        \
  } while (0)

#define ENDBAR_SEQ()                                      \
  do {                                                    \
    __builtin_amdgcn_s_setprio(0);                        \
    asm volatile("" ::: "memory");                        \
    __builtin_amdgcn_s_barrier();                         \
    asm volatile("" ::: "memory");                        \
  } while (0)

#define READA(QM)                                                              \
  do {                                                                         \
    _Pragma("unroll") for (int j = 0; j < MQ; ++j)                             \
    _Pragma("unroll") for (int kk = 0; kk < 2; ++kk) {                         \
      int row = wm * (BM / 2) + ((QM) * MQ + j) * 16 + li;                     \
      int c = (kk * 4 + g) ^ (li & 7);                                         \
      af[j][kk] = *reinterpret_cast<const bf16x8*>(&As[cur][row * 64 + c * 8]);\
    }                                                                          \
  } while (0)

#define READB(BF, QN)                                                          \
  do {                                                                         \
    _Pragma("unroll") for (int jn = 0; jn < 2; ++jn)                           \
    _Pragma("unroll") for (int kk = 0; kk < 2; ++kk) {                         \
      int row = wn * 64 + ((QN) * 2 + jn) * 16 + li;                           \
      int c = (kk * 4 + g) ^ (li & 7);                                         \
      BF[jn][kk] = *reinterpret_cast<const bf16x8*>(&Bs[cur][row * 64 + c * 8]);\
    }                                                                          \
  } while (0)

#define QUAD(QM, QN, BF)                                                       \
  do {                                                                         \
    _Pragma("unroll") for (int j = 0; j < MQ; ++j)                             \
    _Pragma("unroll") for (int jn = 0; jn < 2; ++jn)                           \
    _Pragma("unroll") for (int kk = 0; kk < 2; ++kk)                           \
      acc[(QM) * MQ + j][(QN) * 2 + jn] =                                      \
          __builtin_amdgcn_mfma_f32_16x16x32_bf16(                             \
              af[j][kk], BF[jn][kk], acc[(QM) * MQ + j][(QN) * 2 + jn], 0, 0, 0);\
  } while (0)

template <int BM, bool OUT_F32>
__global__ __launch_bounds__(512, 2) void gemm_8ph_k(
    const unsigned short* __restrict__ A, const unsigned short* __restrict__ B0p,
    const unsigned short* __restrict__ B1p, const unsigned short* __restrict__ B2p,
    void* __restrict__ C0, void* __restrict__ C1, void* __restrict__ C2,
    int M, int N, int K) {
  constexpr int MQ = BM / 64;  // m-frags per quadrant phase
  constexpr int MR = BM / 32;  // m-frags total per wave

  __shared__ unsigned short As[2][BM * 64];
  __shared__ unsigned short Bs[2][256 * 64];

  const unsigned short* Bp = (blockIdx.z == 0) ? B0p : (blockIdx.z == 1) ? B1p : B2p;
  void* Cout = (blockIdx.z == 0) ? C0 : (blockIdx.z == 1) ? C1 : C2;

  // XCD-aware swizzle (gridDim.x divisible by 8)
  int nwg = gridDim.x, bid = blockIdx.x;
  int wg = (bid & 7) * (nwg >> 3) + (bid >> 3);
  int ntn = N >> 8;
  int tm = wg / ntn, tn = wg % ntn;
  int m0 = tm * BM, n0 = tn << 8;

  const int tid = threadIdx.x;
  const int wave = tid >> 6, lane = tid & 63;
  const int g = lane >> 4, li = lane & 15;
  const int wm = wave >> 2, wn = wave & 3;

  // Stage region qn of B tile tt into buffer buf. Region qn = rows
  // {wn*64 + qn*32 + [0,32)} for all 4 wn pieces: 128 rows x 8 chunks
  // = 2 loads/thread. Linear LDS dest, inverse-swizzled global source.
  auto stageB = [&](int buf, int tt, int qn) {
#pragma unroll
    for (int i = 0; i < 2; ++i) {
      int j = i * 512 + tid;
      int piece = j >> 8, rowin = (j >> 3) & 31, c = j & 7;
      int row = piece * 64 + qn * 32 + rowin;
      gload_lds16(Bp + (size_t)(n0 + row) * K + tt * 64 + ((c ^ (row & 7)) * 8),
                  &Bs[buf][row * 64 + c * 8]);
    }
  };
  // Stage region qm of A: rows {wm*(BM/2) + qm*(BM/4) + [0,BM/4)} for both wm
  // pieces: BM/2 rows x 8 chunks = BM/128 loads/thread.
  auto stageA = [&](int buf, int tt, int qm) {
#pragma unroll
    for (int i = 0; i < BM / 128; ++i) {
      int j = i * 512 + tid;
      int piece = j / (2 * BM);                 // = (j>>3) / (BM/4)
      int rowin = (j >> 3) & (BM / 4 - 1);      // FIXED: was & (BM/32-1)
      int c = j & 7;
      int row = piece * (BM / 2) + qm * (BM / 4) + rowin;
      gload_lds16(A + (size_t)(m0 + row) * K + tt * 64 + ((c ^ (row & 7)) * 8),
                  &As[buf][row * 64 + c * 8]);
    }
  };

  f32x4 acc[MR][4];
#pragma unroll
  for (int i = 0; i < MR; ++i)
#pragma unroll
    for (int j = 0; j < 4; ++j) acc[i][j] = (f32x4){0.f, 0.f, 0.f, 0.f};

  const int nK = K >> 6;

  // prologue: tiles 0 and 1, all four regions each
  stageB(0, 0, 0); stageA(0, 0, 0); stageB(0, 0, 1); stageA(0, 0, 1);
  stageB(1, 1, 0); stageA(1, 1, 0); stageB(1, 1, 1); stageA(1, 1, 1);
  if constexpr (BM == 256) asm volatile("s_waitcnt vmcnt(8)" ::: "memory");
  else                     asm volatile("s_waitcnt vmcnt(6)" ::: "memory");
  asm volatile("" ::: "memory");
  __builtin_amdgcn_s_barrier();
  asm volatile("" ::: "memory");

  for (int t = 0; t < nK; ++t) {
    int cur = t & 1;
    bool pf = (t + 2 < nK);
    bf16x8 af[MQ][2], bf0[2][2], bf1[2][2];
    // ---- phase 1: read Aq0,Bq0; no staging; quad(0,0) ----
    READA(0);
    READB(bf0, 0);
    MIDBAR_SEQ();
    QUAD(0, 0, bf0);
    ENDBAR_SEQ();
    // ---- phase 2: read Bq1; stage Aq0+Bq0 (freed by ph1); quad(0,1) ----
    READB(bf1, 1);
    if (pf) { stageB(cur, t + 2, 0); stageA(cur, t + 2, 0); }
    MIDBAR_SEQ();
    QUAD(0, 1, bf1);
    ENDBAR_SEQ();
    // ---- phase 3: read Aq1; stage Bq1 (freed by ph2); quad(1,1) ----
    READA(1);
    if (pf) stageB(cur, t + 2, 1);
    MIDBAR_SEQ();
    QUAD(1, 1, bf1);
    ENDBAR_SEQ();
    // ---- phase 4: stage Aq1 (freed by ph3); K-tile boundary vmcnt; quad(1,0) ----
    if (pf) {
      stageA(cur, t + 2, 1);
      if constexpr (BM == 256) asm volatile("s_waitcnt vmcnt(8)" ::: "memory");
      else                     asm volatile("s_waitcnt vmcnt(6)" ::: "memory");
    } else {
      asm volatile("s_waitcnt vmcnt(0)" ::: "memory");
    }
    MIDBAR_SEQ();
    QUAD(1, 0, bf0);
    ENDBAR_SEQ();
  }

  // epilogue
#pragma unroll
  for (int m = 0; m < MR; ++m) {
#pragma unroll
    for (int n = 0; n < 4; ++n) {
      int row = m0 + wm * (BM / 2) + m * 16 + g * 4;
      int col = n0 + wn * 64 + n * 16 + li;
#pragma unroll
      for (int r = 0; r < 4; ++r) {
        if (OUT_F32)
          reinterpret_cast<float*>(Cout)[(size_t)(row + r) * N + col] = acc[m][n][r];
        else
          reinterpret_cast<unsigned short*>(Cout)[(size_t)(row + r) * N + col] =
              f2b(acc[m][n][r]);
      }
    }
  }
}

#undef MIDBAR_SEQ
#undef ENDBAR_SEQ
#undef READA
#undef READB
#undef QUAD

// ---------------- causal flash attention (round-2, verified) ----------------
__global__ __launch_bounds__(256) void flash_attn_k(
    const unsigned short* __restrict__ q, const unsigned short* __restrict__ k,
    const unsigned short* __restrict__ vt, unsigned short* __restrict__ o) {
  __shared__ unsigned short Ks[2][64 * 128];
  __shared__ unsigned short Vs[2][128 * 64];
  __shared__ unsigned short Ps[4 * 16 * 72];

  int p = blockIdx.x, h = blockIdx.y;
  int t = threadIdx.x, wave = t >> 6, lane = t & 63;
  int g = lane >> 4, li = lane & 15;

  const unsigned short* vth = vt + (size_t)h * HDIM * S_LEN;
  const float sm = 0.08838834764831845f;
  const float L2E = 1.4426950408889634f;

  auto stage = [&](int buf, int kt) {
    int kv0 = kt * 64;
#pragma unroll
    for (int i = 0; i < 4; ++i) {
      int ch = i * 256 + t;
      int row = ch >> 4, c = ch & 15;
      int cs_ = c ^ (row & 7);
      gload_lds16(k + (size_t)(kv0 + row) * DMODEL + h * HDIM + cs_ * 8,
                  &Ks[buf][ch * 8]);
    }
#pragma unroll
    for (int i = 0; i < 4; ++i) {
      int ch = i * 256 + t;
      int row = ch >> 3, c = ch & 7;
      int cs_ = c ^ (row & 7);
      gload_lds16(vth + (size_t)row * S_LEN + kv0 + cs_ * 8,
                  &Vs[buf][ch * 8]);
    }
  };

  for (int seg = 0; seg < 2; ++seg) {
    int qt = seg ? (31 - p) : p;
    int nIter = qt + 1;
    int q0 = qt * 64;
    int qrow = q0 + wave * 16 + li;

    bf16x8 qf[4];
#pragma unroll
    for (int kb = 0; kb < 4; ++kb)
      qf[kb] = *reinterpret_cast<const bf16x8*>(
          q + (size_t)qrow * DMODEL + h * HDIM + kb * 32 + g * 8);

    f32x4 O[8];
#pragma unroll
    for (int db = 0; db < 8; ++db) O[db] = (f32x4){0.f, 0.f, 0.f, 0.f};
    float m_r[4], l_r[4];
#pragma unroll
    for (int r = 0; r < 4; ++r) { m_r[r] = -1e30f; l_r[r] = 0.f; }

    stage(0, 0);

    for (int it = 0; it < nIter; ++it) {
      int cur = it & 1;
      int kv0 = it * 64;
      if (it + 1 < nIter) {
        stage(cur ^ 1, it + 1);
        asm volatile("s_waitcnt vmcnt(8)" ::: "memory");
      } else {
        asm volatile("s_waitcnt vmcnt(0)" ::: "memory");
      }
      __builtin_amdgcn_s_barrier();
      asm volatile("" ::: "memory");

      f32x4 sf[4];
#pragma unroll
      for (int jb = 0; jb < 4; ++jb) sf[jb] = (f32x4){0.f, 0.f, 0.f, 0.f};
#pragma unroll
      for (int kb = 0; kb < 4; ++kb) {
#pragma unroll
        for (int jb = 0; jb < 4; ++jb) {
          int row = jb * 16 + li;
          int c = (kb * 4 + g) ^ (row & 7);
          bf16x8 kf = *reinterpret_cast<const bf16x8*>(&Ks[cur][row * 128 + c * 8]);
          sf[jb] = __builtin_amdgcn_mfma_f32_16x16x32_bf16(qf[kb], kf, sf[jb], 0, 0, 0);
        }
      }

      float sv[4][4];
      float pm[4] = {-1e30f, -1e30f, -1e30f, -1e30f};
#pragma unroll
      for (int jb = 0; jb < 4; ++jb) {
        int jcol = kv0 + jb * 16 + li;
#pragma unroll
        for (int r = 0; r < 4; ++r) {
          float x = sf[jb][r] * sm;
          int irow = q0 + wave * 16 + g * 4 + r;
          if (it == qt && jcol > irow) x = -1e30f;
          sv[jb][r] = x;
          pm[r] = fmaxf(pm[r], x);
        }
      }
#pragma unroll
      for (int r = 0; r < 4; ++r) {
        float x = pm[r];
        x = fmaxf(x, __shfl_xor(x, 1));
        x = fmaxf(x, __shfl_xor(x, 2));
        x = fmaxf(x, __shfl_xor(x, 4));
        x = fmaxf(x, __shfl_xor(x, 8));
        pm[r] = x;
      }
      float alpha[4], ls[4];
#pragma unroll
      for (int r = 0; r < 4; ++r) {
        float nm = fmaxf(m_r[r], pm[r]);
        alpha[r] = exp2f((m_r[r] - nm) * L2E);
        m_r[r] = nm;
        ls[r] = 0.f;
      }
#pragma unroll
      for (int jb = 0; jb < 4; ++jb) {
#pragma unroll
        for (int r = 0; r < 4; ++r) {
          float pv = exp2f((sv[jb][r] - m_r[r]) * L2E);
          ls[r] += pv;
          Ps[wave * 16 * 72 + (g * 4 + r) * 72 + jb * 16 + li] = f2b(pv);
        }
      }
#pragma unroll
      for (int r = 0; r < 4; ++r) {
        float x = ls[r];
        x += __shfl_xor(x, 1);
        x += __shfl_xor(x, 2);
        x += __shfl_xor(x, 4);
        x += __shfl_xor(x, 8);
        l_r[r] = l_r[r] * alpha[r] + x;
      }
#pragma unroll
      for (int db = 0; db < 8; ++db)
#pragma unroll
        for (int r = 0; r < 4; ++r) O[db][r] *= alpha[r];

#pragma unroll
      for (int ks = 0; ks < 2; ++ks) {
        bf16x8 pa = *reinterpret_cast<const bf16x8*>(
            Ps + wave * 16 * 72 + li * 72 + ks * 32 + g * 8);
#pragma unroll
        for (int db = 0; db < 8; ++db) {
          int row = db * 16 + li;
          int c = (ks * 4 + g) ^ (row & 7);
          bf16x8 vbf = *reinterpret_cast<const bf16x8*>(&Vs[cur][row * 64 + c * 8]);
          O[db] = __builtin_amdgcn_mfma_f32_16x16x32_bf16(pa, vbf, O[db], 0, 0, 0);
        }
      }
      __builtin_amdgcn_s_barrier();
      asm volatile("" ::: "memory");
    }

#pragma unroll
    for (int db = 0; db < 8; ++db) {
#pragma unroll
      for (int r = 0; r < 4; ++r) {
        int row = q0 + wave * 16 + g * 4 + r;
        o[(size_t)row * DMODEL + h * HDIM + db * 16 + li] = f2b(O[db][r] / l_r[r]);
      }
    }
  }
}

extern "C" void kernel_launch(void* const* d_in, const int* in_sizes, int n_in,
                              void* d_out, int out_size, void* d_ws, size_t ws_size,
                              hipStream_t stream) {
  const float* hs = (const float*)d_in[0];
  const float* Wq = (const float*)d_in[1];
  const float* Wk = (const float*)d_in[2];
  const float* Wv = (const float*)d_in[3];
  const float* Wo = (const float*)d_in[4];

  char* ws = (char*)d_ws;
  const size_t MB = 1024 * 1024;
  unsigned short* hs_b = (unsigned short*)(ws + 0 * MB);  // reused as vt later
  unsigned short* Wq_b = (unsigned short*)(ws + 8 * MB);
  unsigned short* Wk_b = (unsigned short*)(ws + 16 * MB);
  unsigned short* Wv_b = (unsigned short*)(ws + 24 * MB);
  unsigned short* Wo_b = (unsigned short*)(ws + 32 * MB);
  unsigned short* qb = (unsigned short*)(ws + 40 * MB);
  unsigned short* kb = (unsigned short*)(ws + 48 * MB);
  unsigned short* vb = (unsigned short*)(ws + 56 * MB);
  unsigned short* ab = (unsigned short*)(ws + 64 * MB);
  float* cs = (float*)(ws + 72 * MB);
  float* sn = (float*)(ws + 72 * MB + 512 * 1024);
  unsigned short* vtb = hs_b;  // V^T [h][d][s]; hs_b dead after QKV GEMM

  int n = S_LEN * DMODEL;
  cvt_f32_bf16_k<<<n / 1024, 256, 0, stream>>>(hs, hs_b, n);
  cvt_f32_bf16_k<<<n / 1024, 256, 0, stream>>>(Wq, Wq_b, n);
  cvt_f32_bf16_k<<<n / 1024, 256, 0, stream>>>(Wk, Wk_b, n);
  cvt_f32_bf16_k<<<n / 1024, 256, 0, stream>>>(Wv, Wv_b, n);
  cvt_f32_bf16_k<<<n / 1024, 256, 0, stream>>>(Wo, Wo_b, n);

  rope_table_k<<<(S_LEN * 64) / 256, 256, 0, stream>>>(cs, sn);

  // fused QKV projection: 256x256 tiles, 8-phase pipeline
  gemm_8ph_k<256, false><<<dim3(64, 1, 3), 512, 0, stream>>>(
      hs_b, Wq_b, Wk_b, Wv_b, qb, kb, vb, 2048, 2048, 2048);

  // V -> V^T
  transpose_bf16_k<<<dim3(32, 32), 256, 0, stream>>>(vb, vtb);

  rope_apply_k<<<(S_LEN * NHEADS * 64) / 256, 256, 0, stream>>>(qb, kb, cs, sn);

  flash_attn_k<<<dim3(16, NHEADS), 256, 0, stream>>>(qb, kb, vtb, ab);

  // output projection: 128x256 tiles (128 blocks) -> fp32 d_out
  gemm_8ph_k<128, true><<<dim3(128, 1, 1), 512, 0, stream>>>(
      ab, Wo_b, Wo_b, Wo_b, d_out, d_out, d_out, 2048, 2048, 2048);
}

// Round 5
// 223.518 us; speedup vs baseline: 1.6911x; 1.0575x over previous
//
#include <hip/hip_runtime.h>
#include <hip/hip_bf16.h>
#include <math.h>

#define S_LEN 2048
#define DMODEL 2048
#define NHEADS 16
#define HDIM 128

typedef __bf16 bf16x8 __attribute__((ext_vector_type(8)));
typedef float f32x4 __attribute__((ext_vector_type(4)));

__device__ __forceinline__ unsigned short f2b(float f) {
  union { float f; unsigned u; } c; c.f = f;
  unsigned r = (c.u + 0x7fffu + ((c.u >> 16) & 1u)) >> 16;
  return (unsigned short)r;
}
__device__ __forceinline__ float b2f(unsigned short b) {
  union { unsigned u; float f; } c; c.u = ((unsigned)b) << 16;
  return c.f;
}

__device__ __forceinline__ void gload_lds16(const unsigned short* g, unsigned short* l) {
  __builtin_amdgcn_global_load_lds(
      (__attribute__((address_space(1))) void*)(void*)g,
      (__attribute__((address_space(3))) void*)(void*)l, 16, 0, 0);
}

// ---------------- fused fp32 -> bf16 conversion (5 tensors, one launch) ----
__global__ void cvt5_f32_bf16_k(const float* __restrict__ s0,
                                const float* __restrict__ s1,
                                const float* __restrict__ s2,
                                const float* __restrict__ s3,
                                const float* __restrict__ s4,
                                unsigned short* __restrict__ d0,
                                unsigned short* __restrict__ d1,
                                unsigned short* __restrict__ d2,
                                unsigned short* __restrict__ d3,
                                unsigned short* __restrict__ d4) {
  int gi = blockIdx.x * blockDim.x + threadIdx.x;  // 5 * 1M threads
  int seg = gi >> 20;                              // 4M elems / 4 per thread
  int i = (gi & 0xFFFFF) * 4;
  const float* src = (seg == 0) ? s0 : (seg == 1) ? s1 : (seg == 2) ? s2
                     : (seg == 3) ? s3 : s4;
  unsigned short* dst = (seg == 0) ? d0 : (seg == 1) ? d1 : (seg == 2) ? d2
                        : (seg == 3) ? d3 : d4;
  float4 v = *reinterpret_cast<const float4*>(src + i);
  ushort4 o;
  o.x = f2b(v.x); o.y = f2b(v.y); o.z = f2b(v.z); o.w = f2b(v.w);
  *reinterpret_cast<ushort4*>(dst + i) = o;
}

// ---------------- RoPE cos/sin table ----------------
__global__ void rope_table_k(float* __restrict__ cs, float* __restrict__ sn) {
  int idx = blockIdx.x * blockDim.x + threadIdx.x;  // S_LEN * 64
  int s = idx >> 6, i = idx & 63;
  float inv = powf(10000.0f, -(float)(2 * i) / 128.0f);
  float a = (float)s * inv;
  cs[idx] = cosf(a);
  sn[idx] = sinf(a);
}

// ---------------- RoPE apply (in-place on q,k bf16) ----------------
__global__ void rope_apply_k(unsigned short* __restrict__ q,
                             unsigned short* __restrict__ k,
                             const float* __restrict__ cs,
                             const float* __restrict__ sn) {
  int idx = blockIdx.x * blockDim.x + threadIdx.x;  // S*H*64
  int i = idx & 63;
  int h = (idx >> 6) & (NHEADS - 1);
  int s = idx >> 10;
  size_t base = (size_t)s * DMODEL + h * HDIM;
  float c = cs[s * 64 + i], sv = sn[s * 64 + i];
  float q1 = b2f(q[base + i]), q2 = b2f(q[base + i + 64]);
  q[base + i]      = f2b(q1 * c - q2 * sv);
  q[base + i + 64] = f2b(q2 * c + q1 * sv);
  float k1 = b2f(k[base + i]), k2 = b2f(k[base + i + 64]);
  k[base + i]      = f2b(k1 * c - k2 * sv);
  k[base + i + 64] = f2b(k2 * c + k1 * sv);
}

// ---------------- bf16 2048x2048 transpose ----------------
__global__ __launch_bounds__(256) void transpose_bf16_k(
    const unsigned short* __restrict__ in, unsigned short* __restrict__ out) {
  __shared__ unsigned short tile[64][72];
  int bx = blockIdx.x, by = blockIdx.y;
  int t = threadIdx.x;
#pragma unroll
  for (int i = 0; i < 2; ++i) {
    int ch = i * 256 + t;
    int r = ch >> 3, c8 = ch & 7;
    bf16x8 v = *reinterpret_cast<const bf16x8*>(
        in + (size_t)(by * 64 + r) * DMODEL + bx * 64 + c8 * 8);
    *reinterpret_cast<bf16x8*>(&tile[r][c8 * 8]) = v;
  }
  __syncthreads();
#pragma unroll
  for (int i = 0; i < 2; ++i) {
    int ch = i * 256 + t;
    int c = ch >> 3, r8 = ch & 7;
    union { bf16x8 v; unsigned short u[8]; } w;
#pragma unroll
    for (int j = 0; j < 8; ++j) w.u[j] = tile[r8 * 8 + j][c];
    *reinterpret_cast<bf16x8*>(
        out + (size_t)(bx * 64 + c) * S_LEN + by * 64 + r8 * 8) = w.v;
  }
}

// ============ 8-phase 256-wide NT GEMM (m201-style, plain HIP) ============
// (unchanged from round 4 — verified correct)

#define MIDBAR_SEQ()                                      \
  do {                                                    \
    asm volatile("" ::: "memory");                        \
    __builtin_amdgcn_s_barrier();                         \
    asm volatile("s_waitcnt lgkmcnt(0)" ::: "memory");    \
    __builtin_amdgcn_sched_barrier(0);                    \
    __builtin_amdgcn_s_setprio(1);                        \
  } while (0)

#define ENDBAR_SEQ()                                      \
  do {                                                    \
    __builtin_amdgcn_s_setprio(0);                        \
    asm volatile("" ::: "memory");                        \
    __builtin_amdgcn_s_barrier();                         \
    asm volatile("" ::: "memory");                        \
  } while (0)

#define READA(QM)                                                              \
  do {                                                                         \
    _Pragma("unroll") for (int j = 0; j < MQ; ++j)                             \
    _Pragma("unroll") for (int kk = 0; kk < 2; ++kk) {                         \
      int row = wm * (BM / 2) + ((QM) * MQ + j) * 16 + li;                     \
      int c = (kk * 4 + g) ^ (li & 7);                                         \
      af[j][kk] = *reinterpret_cast<const bf16x8*>(&As[cur][row * 64 + c * 8]);\
    }                                                                          \
  } while (0)

#define READB(BF, QN)                                                          \
  do {                                                                         \
    _Pragma("unroll") for (int jn = 0; jn < 2; ++jn)                           \
    _Pragma("unroll") for (int kk = 0; kk < 2; ++kk) {                         \
      int row = wn * 64 + ((QN) * 2 + jn) * 16 + li;                           \
      int c = (kk * 4 + g) ^ (li & 7);                                         \
      BF[jn][kk] = *reinterpret_cast<const bf16x8*>(&Bs[cur][row * 64 + c * 8]);\
    }                                                                          \
  } while (0)

#define QUAD(QM, QN, BF)                                                       \
  do {                                                                         \
    _Pragma("unroll") for (int j = 0; j < MQ; ++j)                             \
    _Pragma("unroll") for (int jn = 0; jn < 2; ++jn)                           \
    _Pragma("unroll") for (int kk = 0; kk < 2; ++kk)                           \
      acc[(QM) * MQ + j][(QN) * 2 + jn] =                                      \
          __builtin_amdgcn_mfma_f32_16x16x32_bf16(                             \
              af[j][kk], BF[jn][kk], acc[(QM) * MQ + j][(QN) * 2 + jn], 0, 0, 0);\
  } while (0)

template <int BM, bool OUT_F32>
__global__ __launch_bounds__(512, 2) void gemm_8ph_k(
    const unsigned short* __restrict__ A, const unsigned short* __restrict__ B0p,
    const unsigned short* __restrict__ B1p, const unsigned short* __restrict__ B2p,
    void* __restrict__ C0, void* __restrict__ C1, void* __restrict__ C2,
    int M, int N, int K) {
  constexpr int MQ = BM / 64;
  constexpr int MR = BM / 32;

  __shared__ unsigned short As[2][BM * 64];
  __shared__ unsigned short Bs[2][256 * 64];

  const unsigned short* Bp = (blockIdx.z == 0) ? B0p : (blockIdx.z == 1) ? B1p : B2p;
  void* Cout = (blockIdx.z == 0) ? C0 : (blockIdx.z == 1) ? C1 : C2;

  int nwg = gridDim.x, bid = blockIdx.x;
  int wg = (bid & 7) * (nwg >> 3) + (bid >> 3);
  int ntn = N >> 8;
  int tm = wg / ntn, tn = wg % ntn;
  int m0 = tm * BM, n0 = tn << 8;

  const int tid = threadIdx.x;
  const int wave = tid >> 6, lane = tid & 63;
  const int g = lane >> 4, li = lane & 15;
  const int wm = wave >> 2, wn = wave & 3;

  auto stageB = [&](int buf, int tt, int qn) {
#pragma unroll
    for (int i = 0; i < 2; ++i) {
      int j = i * 512 + tid;
      int piece = j >> 8, rowin = (j >> 3) & 31, c = j & 7;
      int row = piece * 64 + qn * 32 + rowin;
      gload_lds16(Bp + (size_t)(n0 + row) * K + tt * 64 + ((c ^ (row & 7)) * 8),
                  &Bs[buf][row * 64 + c * 8]);
    }
  };
  auto stageA = [&](int buf, int tt, int qm) {
#pragma unroll
    for (int i = 0; i < BM / 128; ++i) {
      int j = i * 512 + tid;
      int piece = j / (2 * BM);
      int rowin = (j >> 3) & (BM / 4 - 1);
      int c = j & 7;
      int row = piece * (BM / 2) + qm * (BM / 4) + rowin;
      gload_lds16(A + (size_t)(m0 + row) * K + tt * 64 + ((c ^ (row & 7)) * 8),
                  &As[buf][row * 64 + c * 8]);
    }
  };

  f32x4 acc[MR][4];
#pragma unroll
  for (int i = 0; i < MR; ++i)
#pragma unroll
    for (int j = 0; j < 4; ++j) acc[i][j] = (f32x4){0.f, 0.f, 0.f, 0.f};

  const int nK = K >> 6;

  stageB(0, 0, 0); stageA(0, 0, 0); stageB(0, 0, 1); stageA(0, 0, 1);
  stageB(1, 1, 0); stageA(1, 1, 0); stageB(1, 1, 1); stageA(1, 1, 1);
  if constexpr (BM == 256) asm volatile("s_waitcnt vmcnt(8)" ::: "memory");
  else                     asm volatile("s_waitcnt vmcnt(6)" ::: "memory");
  asm volatile("" ::: "memory");
  __builtin_amdgcn_s_barrier();
  asm volatile("" ::: "memory");

  for (int t = 0; t < nK; ++t) {
    int cur = t & 1;
    bool pf = (t + 2 < nK);
    bf16x8 af[MQ][2], bf0[2][2], bf1[2][2];
    // ---- phase 1: read Aq0,Bq0; quad(0,0) ----
    READA(0);
    READB(bf0, 0);
    MIDBAR_SEQ();
    QUAD(0, 0, bf0);
    ENDBAR_SEQ();
    // ---- phase 2: read Bq1; stage Aq0+Bq0; quad(0,1) ----
    READB(bf1, 1);
    if (pf) { stageB(cur, t + 2, 0); stageA(cur, t + 2, 0); }
    MIDBAR_SEQ();
    QUAD(0, 1, bf1);
    ENDBAR_SEQ();
    // ---- phase 3: read Aq1; stage Bq1; quad(1,1) ----
    READA(1);
    if (pf) stageB(cur, t + 2, 1);
    MIDBAR_SEQ();
    QUAD(1, 1, bf1);
    ENDBAR_SEQ();
    // ---- phase 4: stage Aq1; K-tile boundary vmcnt; quad(1,0) ----
    if (pf) {
      stageA(cur, t + 2, 1);
      if constexpr (BM == 256) asm volatile("s_waitcnt vmcnt(8)" ::: "memory");
      else                     asm volatile("s_waitcnt vmcnt(6)" ::: "memory");
    } else {
      asm volatile("s_waitcnt vmcnt(0)" ::: "memory");
    }
    MIDBAR_SEQ();
    QUAD(1, 0, bf0);
    ENDBAR_SEQ();
  }

#pragma unroll
  for (int m = 0; m < MR; ++m) {
#pragma unroll
    for (int n = 0; n < 4; ++n) {
      int row = m0 + wm * (BM / 2) + m * 16 + g * 4;
      int col = n0 + wn * 64 + n * 16 + li;
#pragma unroll
      for (int r = 0; r < 4; ++r) {
        if (OUT_F32)
          reinterpret_cast<float*>(Cout)[(size_t)(row + r) * N + col] = acc[m][n][r];
        else
          reinterpret_cast<unsigned short*>(Cout)[(size_t)(row + r) * N + col] =
              f2b(acc[m][n][r]);
      }
    }
  }
}

#undef MIDBAR_SEQ
#undef ENDBAR_SEQ
#undef READA
#undef READB
#undef QUAD

// ---------------- causal flash attention ----------------
// 256 blocks (16 pairs x 16 heads), 4 waves. XCD-locality swizzle: hardware
// assigns XCD = linear_bid % 8; remap so XCD x serves only heads {2x, 2x+1}
// (2 MB K/V working set < 4 MB per-XCD L2; was: all 16 heads -> L2 thrash,
// 121 MB HBM fetch). Pairing {p, 31-p} keeps all blocks at 33 tile-iters.
__global__ __launch_bounds__(256) void flash_attn_k(
    const unsigned short* __restrict__ q, const unsigned short* __restrict__ k,
    const unsigned short* __restrict__ vt, unsigned short* __restrict__ o) {
  __shared__ unsigned short Ks[2][64 * 128];
  __shared__ unsigned short Vs[2][128 * 64];
  __shared__ unsigned short Ps[4 * 16 * 72];

  int L = blockIdx.x + 16 * blockIdx.y;  // dispatch-linear id
  int xcd = L & 7, j = L >> 3;
  int h = 2 * xcd + (j & 1);
  int p = j >> 1;

  int t = threadIdx.x, wave = t >> 6, lane = t & 63;
  int g = lane >> 4, li = lane & 15;

  const unsigned short* vth = vt + (size_t)h * HDIM * S_LEN;
  const float sm = 0.08838834764831845f;
  const float L2E = 1.4426950408889634f;

  auto stage = [&](int buf, int kt) {
    int kv0 = kt * 64;
#pragma unroll
    for (int i = 0; i < 4; ++i) {
      int ch = i * 256 + t;
      int row = ch >> 4, c = ch & 15;
      int cs_ = c ^ (row & 7);
      gload_lds16(k + (size_t)(kv0 + row) * DMODEL + h * HDIM + cs_ * 8,
                  &Ks[buf][ch * 8]);
    }
#pragma unroll
    for (int i = 0; i < 4; ++i) {
      int ch = i * 256 + t;
      int row = ch >> 3, c = ch & 7;
      int cs_ = c ^ (row & 7);
      gload_lds16(vth + (size_t)row * S_LEN + kv0 + cs_ * 8,
                  &Vs[buf][ch * 8]);
    }
  };

  for (int seg = 0; seg < 2; ++seg) {
    int qt = seg ? (31 - p) : p;
    int nIter = qt + 1;
    int q0 = qt * 64;
    int qrow = q0 + wave * 16 + li;

    bf16x8 qf[4];
#pragma unroll
    for (int kb = 0; kb < 4; ++kb)
      qf[kb] = *reinterpret_cast<const bf16x8*>(
          q + (size_t)qrow * DMODEL + h * HDIM + kb * 32 + g * 8);

    f32x4 O[8];
#pragma unroll
    for (int db = 0; db < 8; ++db) O[db] = (f32x4){0.f, 0.f, 0.f, 0.f};
    float m_r[4], l_r[4];
#pragma unroll
    for (int r = 0; r < 4; ++r) { m_r[r] = -1e30f; l_r[r] = 0.f; }

    stage(0, 0);

    for (int it = 0; it < nIter; ++it) {
      int cur = it & 1;
      int kv0 = it * 64;
      if (it + 1 < nIter) {
        stage(cur ^ 1, it + 1);
        asm volatile("s_waitcnt vmcnt(8)" ::: "memory");
      } else {
        asm volatile("s_waitcnt vmcnt(0)" ::: "memory");
      }
      __builtin_amdgcn_s_barrier();
      asm volatile("" ::: "memory");

      f32x4 sf[4];
#pragma unroll
      for (int jb = 0; jb < 4; ++jb) sf[jb] = (f32x4){0.f, 0.f, 0.f, 0.f};
#pragma unroll
      for (int kb = 0; kb < 4; ++kb) {
#pragma unroll
        for (int jb = 0; jb < 4; ++jb) {
          int row = jb * 16 + li;
          int c = (kb * 4 + g) ^ (row & 7);
          bf16x8 kf = *reinterpret_cast<const bf16x8*>(&Ks[cur][row * 128 + c * 8]);
          sf[jb] = __builtin_amdgcn_mfma_f32_16x16x32_bf16(qf[kb], kf, sf[jb], 0, 0, 0);
        }
      }

      float sv[4][4];
      float pm[4] = {-1e30f, -1e30f, -1e30f, -1e30f};
#pragma unroll
      for (int jb = 0; jb < 4; ++jb) {
        int jcol = kv0 + jb * 16 + li;
#pragma unroll
        for (int r = 0; r < 4; ++r) {
          float x = sf[jb][r] * sm;
          int irow = q0 + wave * 16 + g * 4 + r;
          if (it == qt && jcol > irow) x = -1e30f;
          sv[jb][r] = x;
          pm[r] = fmaxf(pm[r], x);
        }
      }
#pragma unroll
      for (int r = 0; r < 4; ++r) {
        float x = pm[r];
        x = fmaxf(x, __shfl_xor(x, 1));
        x = fmaxf(x, __shfl_xor(x, 2));
        x = fmaxf(x, __shfl_xor(x, 4));
        x = fmaxf(x, __shfl_xor(x, 8));
        pm[r] = x;
      }
      float alpha[4], ls[4];
#pragma unroll
      for (int r = 0; r < 4; ++r) {
        float nm = fmaxf(m_r[r], pm[r]);
        alpha[r] = exp2f((m_r[r] - nm) * L2E);
        m_r[r] = nm;
        ls[r] = 0.f;
      }
#pragma unroll
      for (int jb = 0; jb < 4; ++jb) {
#pragma unroll
        for (int r = 0; r < 4; ++r) {
          float pv = exp2f((sv[jb][r] - m_r[r]) * L2E);
          ls[r] += pv;
          Ps[wave * 16 * 72 + (g * 4 + r) * 72 + jb * 16 + li] = f2b(pv);
        }
      }
#pragma unroll
      for (int r = 0; r < 4; ++r) {
        float x = ls[r];
        x += __shfl_xor(x, 1);
        x += __shfl_xor(x, 2);
        x += __shfl_xor(x, 4);
        x += __shfl_xor(x, 8);
        l_r[r] = l_r[r] * alpha[r] + x;
      }
#pragma unroll
      for (int db = 0; db < 8; ++db)
#pragma unroll
        for (int r = 0; r < 4; ++r) O[db][r] *= alpha[r];

#pragma unroll
      for (int ks = 0; ks < 2; ++ks) {
        bf16x8 pa = *reinterpret_cast<const bf16x8*>(
            Ps + wave * 16 * 72 + li * 72 + ks * 32 + g * 8);
#pragma unroll
        for (int db = 0; db < 8; ++db) {
          int row = db * 16 + li;
          int c = (ks * 4 + g) ^ (row & 7);
          bf16x8 vbf = *reinterpret_cast<const bf16x8*>(&Vs[cur][row * 64 + c * 8]);
          O[db] = __builtin_amdgcn_mfma_f32_16x16x32_bf16(pa, vbf, O[db], 0, 0, 0);
        }
      }
      __builtin_amdgcn_s_barrier();
      asm volatile("" ::: "memory");
    }

#pragma unroll
    for (int db = 0; db < 8; ++db) {
#pragma unroll
      for (int r = 0; r < 4; ++r) {
        int row = q0 + wave * 16 + g * 4 + r;
        o[(size_t)row * DMODEL + h * HDIM + db * 16 + li] = f2b(O[db][r] / l_r[r]);
      }
    }
  }
}

extern "C" void kernel_launch(void* const* d_in, const int* in_sizes, int n_in,
                              void* d_out, int out_size, void* d_ws, size_t ws_size,
                              hipStream_t stream) {
  const float* hs = (const float*)d_in[0];
  const float* Wq = (const float*)d_in[1];
  const float* Wk = (const float*)d_in[2];
  const float* Wv = (const float*)d_in[3];
  const float* Wo = (const float*)d_in[4];

  char* ws = (char*)d_ws;
  const size_t MB = 1024 * 1024;
  unsigned short* hs_b = (unsigned short*)(ws + 0 * MB);  // reused as vt later
  unsigned short* Wq_b = (unsigned short*)(ws + 8 * MB);
  unsigned short* Wk_b = (unsigned short*)(ws + 16 * MB);
  unsigned short* Wv_b = (unsigned short*)(ws + 24 * MB);
  unsigned short* Wo_b = (unsigned short*)(ws + 32 * MB);
  unsigned short* qb = (unsigned short*)(ws + 40 * MB);
  unsigned short* kb = (unsigned short*)(ws + 48 * MB);
  unsigned short* vb = (unsigned short*)(ws + 56 * MB);
  unsigned short* ab = (unsigned short*)(ws + 64 * MB);
  float* cs = (float*)(ws + 72 * MB);
  float* sn = (float*)(ws + 72 * MB + 512 * 1024);
  unsigned short* vtb = hs_b;  // V^T [h][d][s]; hs_b dead after QKV GEMM

  // fused conversion: 5 x 4M elements, 4/thread -> 5M threads
  cvt5_f32_bf16_k<<<(5 * 1024 * 1024) / 256, 256, 0, stream>>>(
      hs, Wq, Wk, Wv, Wo, hs_b, Wq_b, Wk_b, Wv_b, Wo_b);

  rope_table_k<<<(S_LEN * 64) / 256, 256, 0, stream>>>(cs, sn);

  // fused QKV projection: 256x256 tiles, 8-phase pipeline
  gemm_8ph_k<256, false><<<dim3(64, 1, 3), 512, 0, stream>>>(
      hs_b, Wq_b, Wk_b, Wv_b, qb, kb, vb, 2048, 2048, 2048);

  // V -> V^T
  transpose_bf16_k<<<dim3(32, 32), 256, 0, stream>>>(vb, vtb);

  rope_apply_k<<<(S_LEN * NHEADS * 64) / 256, 256, 0, stream>>>(qb, kb, cs, sn);

  flash_attn_k<<<dim3(16, NHEADS), 256, 0, stream>>>(qb, kb, vtb, ab);

  // output projection: 128x256 tiles (128 blocks) -> fp32 d_out
  gemm_8ph_k<128, true><<<dim3(128, 1, 1), 512, 0, stream>>>(
      ab, Wo_b, Wo_b, Wo_b, d_out, d_out, d_out, 2048, 2048, 2048);
}

// Round 6
// 218.819 us; speedup vs baseline: 1.7274x; 1.0215x over previous
//
#include <hip/hip_runtime.h>
#include <hip/hip_bf16.h>
#include <math.h>

#define S_LEN 2048
#define DMODEL 2048
#define NHEADS 16
#define HDIM 128

typedef __bf16 bf16x8 __attribute__((ext_vector_type(8)));
typedef float f32x4 __attribute__((ext_vector_type(4)));

__device__ __forceinline__ unsigned short f2b(float f) {
  union { float f; unsigned u; } c; c.f = f;
  unsigned r = (c.u + 0x7fffu + ((c.u >> 16) & 1u)) >> 16;
  return (unsigned short)r;
}
__device__ __forceinline__ float b2f(unsigned short b) {
  union { unsigned u; float f; } c; c.u = ((unsigned)b) << 16;
  return c.f;
}

__device__ __forceinline__ void gload_lds16(const unsigned short* g, unsigned short* l) {
  __builtin_amdgcn_global_load_lds(
      (__attribute__((address_space(1))) void*)(void*)g,
      (__attribute__((address_space(3))) void*)(void*)l, 16, 0, 0);
}

// ---------------- fused fp32 -> bf16 conversion (5 tensors, one launch) ----
__global__ void cvt5_f32_bf16_k(const float* __restrict__ s0,
                                const float* __restrict__ s1,
                                const float* __restrict__ s2,
                                const float* __restrict__ s3,
                                const float* __restrict__ s4,
                                unsigned short* __restrict__ d0,
                                unsigned short* __restrict__ d1,
                                unsigned short* __restrict__ d2,
                                unsigned short* __restrict__ d3,
                                unsigned short* __restrict__ d4) {
  int gi = blockIdx.x * blockDim.x + threadIdx.x;
  int seg = gi >> 20;
  int i = (gi & 0xFFFFF) * 4;
  const float* src = (seg == 0) ? s0 : (seg == 1) ? s1 : (seg == 2) ? s2
                     : (seg == 3) ? s3 : s4;
  unsigned short* dst = (seg == 0) ? d0 : (seg == 1) ? d1 : (seg == 2) ? d2
                        : (seg == 3) ? d3 : d4;
  float4 v = *reinterpret_cast<const float4*>(src + i);
  ushort4 o;
  o.x = f2b(v.x); o.y = f2b(v.y); o.z = f2b(v.z); o.w = f2b(v.w);
  *reinterpret_cast<ushort4*>(dst + i) = o;
}

// ---------------- RoPE cos/sin table ----------------
__global__ void rope_table_k(float* __restrict__ cs, float* __restrict__ sn) {
  int idx = blockIdx.x * blockDim.x + threadIdx.x;  // S_LEN * 64
  int s = idx >> 6, i = idx & 63;
  float inv = powf(10000.0f, -(float)(2 * i) / 128.0f);
  float a = (float)s * inv;
  cs[idx] = cosf(a);
  sn[idx] = sinf(a);
}

// ---------------- RoPE apply (in-place on q,k bf16) ----------------
// q additionally scaled by sm*log2(e): attention softmax then runs in the
// log2 domain with no per-score scaling.
__global__ void rope_apply_k(unsigned short* __restrict__ q,
                             unsigned short* __restrict__ k,
                             const float* __restrict__ cs,
                             const float* __restrict__ sn) {
  const float SC = 0.08838834764831845f * 1.4426950408889634f;  // sm * log2e
  int idx = blockIdx.x * blockDim.x + threadIdx.x;  // S*H*64
  int i = idx & 63;
  int h = (idx >> 6) & (NHEADS - 1);
  int s = idx >> 10;
  size_t base = (size_t)s * DMODEL + h * HDIM;
  float c = cs[s * 64 + i], sv = sn[s * 64 + i];
  float qc = c * SC, qs = sv * SC;
  float q1 = b2f(q[base + i]), q2 = b2f(q[base + i + 64]);
  q[base + i]      = f2b(q1 * qc - q2 * qs);
  q[base + i + 64] = f2b(q2 * qc + q1 * qs);
  float k1 = b2f(k[base + i]), k2 = b2f(k[base + i + 64]);
  k[base + i]      = f2b(k1 * c - k2 * sv);
  k[base + i + 64] = f2b(k2 * c + k1 * sv);
}

// ---------------- bf16 2048x2048 transpose ----------------
__global__ __launch_bounds__(256) void transpose_bf16_k(
    const unsigned short* __restrict__ in, unsigned short* __restrict__ out) {
  __shared__ unsigned short tile[64][72];
  int bx = blockIdx.x, by = blockIdx.y;
  int t = threadIdx.x;
#pragma unroll
  for (int i = 0; i < 2; ++i) {
    int ch = i * 256 + t;
    int r = ch >> 3, c8 = ch & 7;
    bf16x8 v = *reinterpret_cast<const bf16x8*>(
        in + (size_t)(by * 64 + r) * DMODEL + bx * 64 + c8 * 8);
    *reinterpret_cast<bf16x8*>(&tile[r][c8 * 8]) = v;
  }
  __syncthreads();
#pragma unroll
  for (int i = 0; i < 2; ++i) {
    int ch = i * 256 + t;
    int c = ch >> 3, r8 = ch & 7;
    union { bf16x8 v; unsigned short u[8]; } w;
#pragma unroll
    for (int j = 0; j < 8; ++j) w.u[j] = tile[r8 * 8 + j][c];
    *reinterpret_cast<bf16x8*>(
        out + (size_t)(bx * 64 + c) * S_LEN + by * 64 + r8 * 8) = w.v;
  }
}

// ============ 8-phase 256-wide NT GEMM (unchanged, verified) ============

#define MIDBAR_SEQ()                                      \
  do {                                                    \
    asm volatile("" ::: "memory");                        \
    __builtin_amdgcn_s_barrier();                         \
    asm volatile("s_waitcnt lgkmcnt(0)" ::: "memory");    \
    __builtin_amdgcn_sched_barrier(0);                    \
    __builtin_amdgcn_s_setprio(1);                        \
  } while (0)

#define ENDBAR_SEQ()                                      \
  do {                                                    \
    __builtin_amdgcn_s_setprio(0);                        \
    asm volatile("" ::: "memory");                        \
    __builtin_amdgcn_s_barrier();                         \
    asm volatile("" ::: "memory");                        \
  } while (0)

#define READA(QM)                                                              \
  do {                                                                         \
    _Pragma("unroll") for (int j = 0; j < MQ; ++j)                             \
    _Pragma("unroll") for (int kk = 0; kk < 2; ++kk) {                         \
      int row = wm * (BM / 2) + ((QM) * MQ + j) * 16 + li;                     \
      int c = (kk * 4 + g) ^ (li & 7);                                         \
      af[j][kk] = *reinterpret_cast<const bf16x8*>(&As[cur][row * 64 + c * 8]);\
    }                                                                          \
  } while (0)

#define READB(BF, QN)                                                          \
  do {                                                                         \
    _Pragma("unroll") for (int jn = 0; jn < 2; ++jn)                           \
    _Pragma("unroll") for (int kk = 0; kk < 2; ++kk) {                         \
      int row = wn * 64 + ((QN) * 2 + jn) * 16 + li;                           \
      int c = (kk * 4 + g) ^ (li & 7);                                         \
      BF[jn][kk] = *reinterpret_cast<const bf16x8*>(&Bs[cur][row * 64 + c * 8]);\
    }                                                                          \
  } while (0)

#define QUAD(QM, QN, BF)                                                       \
  do {                                                                         \
    _Pragma("unroll") for (int j = 0; j < MQ; ++j)                             \
    _Pragma("unroll") for (int jn = 0; jn < 2; ++jn)                           \
    _Pragma("unroll") for (int kk = 0; kk < 2; ++kk)                           \
      acc[(QM) * MQ + j][(QN) * 2 + jn] =                                      \
          __builtin_amdgcn_mfma_f32_16x16x32_bf16(                             \
              af[j][kk], BF[jn][kk], acc[(QM) * MQ + j][(QN) * 2 + jn], 0, 0, 0);\
  } while (0)

template <int BM, bool OUT_F32>
__global__ __launch_bounds__(512, 2) void gemm_8ph_k(
    const unsigned short* __restrict__ A, const unsigned short* __restrict__ B0p,
    const unsigned short* __restrict__ B1p, const unsigned short* __restrict__ B2p,
    void* __restrict__ C0, void* __restrict__ C1, void* __restrict__ C2,
    int M, int N, int K) {
  constexpr int MQ = BM / 64;
  constexpr int MR = BM / 32;

  __shared__ unsigned short As[2][BM * 64];
  __shared__ unsigned short Bs[2][256 * 64];

  const unsigned short* Bp = (blockIdx.z == 0) ? B0p : (blockIdx.z == 1) ? B1p : B2p;
  void* Cout = (blockIdx.z == 0) ? C0 : (blockIdx.z == 1) ? C1 : C2;

  int nwg = gridDim.x, bid = blockIdx.x;
  int wg = (bid & 7) * (nwg >> 3) + (bid >> 3);
  int ntn = N >> 8;
  int tm = wg / ntn, tn = wg % ntn;
  int m0 = tm * BM, n0 = tn << 8;

  const int tid = threadIdx.x;
  const int wave = tid >> 6, lane = tid & 63;
  const int g = lane >> 4, li = lane & 15;
  const int wm = wave >> 2, wn = wave & 3;

  auto stageB = [&](int buf, int tt, int qn) {
#pragma unroll
    for (int i = 0; i < 2; ++i) {
      int j = i * 512 + tid;
      int piece = j >> 8, rowin = (j >> 3) & 31, c = j & 7;
      int row = piece * 64 + qn * 32 + rowin;
      gload_lds16(Bp + (size_t)(n0 + row) * K + tt * 64 + ((c ^ (row & 7)) * 8),
                  &Bs[buf][row * 64 + c * 8]);
    }
  };
  auto stageA = [&](int buf, int tt, int qm) {
#pragma unroll
    for (int i = 0; i < BM / 128; ++i) {
      int j = i * 512 + tid;
      int piece = j / (2 * BM);
      int rowin = (j >> 3) & (BM / 4 - 1);
      int c = j & 7;
      int row = piece * (BM / 2) + qm * (BM / 4) + rowin;
      gload_lds16(A + (size_t)(m0 + row) * K + tt * 64 + ((c ^ (row & 7)) * 8),
                  &As[buf][row * 64 + c * 8]);
    }
  };

  f32x4 acc[MR][4];
#pragma unroll
  for (int i = 0; i < MR; ++i)
#pragma unroll
    for (int j = 0; j < 4; ++j) acc[i][j] = (f32x4){0.f, 0.f, 0.f, 0.f};

  const int nK = K >> 6;

  stageB(0, 0, 0); stageA(0, 0, 0); stageB(0, 0, 1); stageA(0, 0, 1);
  stageB(1, 1, 0); stageA(1, 1, 0); stageB(1, 1, 1); stageA(1, 1, 1);
  if constexpr (BM == 256) asm volatile("s_waitcnt vmcnt(8)" ::: "memory");
  else                     asm volatile("s_waitcnt vmcnt(6)" ::: "memory");
  asm volatile("" ::: "memory");
  __builtin_amdgcn_s_barrier();
  asm volatile("" ::: "memory");

  for (int t = 0; t < nK; ++t) {
    int cur = t & 1;
    bool pf = (t + 2 < nK);
    bf16x8 af[MQ][2], bf0[2][2], bf1[2][2];
    READA(0);
    READB(bf0, 0);
    MIDBAR_SEQ();
    QUAD(0, 0, bf0);
    ENDBAR_SEQ();
    READB(bf1, 1);
    if (pf) { stageB(cur, t + 2, 0); stageA(cur, t + 2, 0); }
    MIDBAR_SEQ();
    QUAD(0, 1, bf1);
    ENDBAR_SEQ();
    READA(1);
    if (pf) stageB(cur, t + 2, 1);
    MIDBAR_SEQ();
    QUAD(1, 1, bf1);
    ENDBAR_SEQ();
    if (pf) {
      stageA(cur, t + 2, 1);
      if constexpr (BM == 256) asm volatile("s_waitcnt vmcnt(8)" ::: "memory");
      else                     asm volatile("s_waitcnt vmcnt(6)" ::: "memory");
    } else {
      asm volatile("s_waitcnt vmcnt(0)" ::: "memory");
    }
    MIDBAR_SEQ();
    QUAD(1, 0, bf0);
    ENDBAR_SEQ();
  }

#pragma unroll
  for (int m = 0; m < MR; ++m) {
#pragma unroll
    for (int n = 0; n < 4; ++n) {
      int row = m0 + wm * (BM / 2) + m * 16 + g * 4;
      int col = n0 + wn * 64 + n * 16 + li;
#pragma unroll
      for (int r = 0; r < 4; ++r) {
        if (OUT_F32)
          reinterpret_cast<float*>(Cout)[(size_t)(row + r) * N + col] = acc[m][n][r];
        else
          reinterpret_cast<unsigned short*>(Cout)[(size_t)(row + r) * N + col] =
              f2b(acc[m][n][r]);
      }
    }
  }
}

#undef MIDBAR_SEQ
#undef ENDBAR_SEQ
#undef READA
#undef READB
#undef QUAD

// ---------------- causal flash attention v3 ----------------
// 512 blocks (one 64-row q-tile each), 4 waves, 2 blocks/CU co-resident.
// Mapping keeps 2 heads per XCD (L2 locality, proven round 5) and pairs
// block L with L+256 so per-CU work sums to 33 tile-iters (LPT order).
// Softmax in log2 domain (q pre-scaled by sm*log2e in RoPE). Diagonal tile
// split out of the bulk loop (no mask VALU in bulk). Row-sum l computed by
// ones-vector MFMA riding the PV accumulator (same alpha recurrence as O).
__global__ __launch_bounds__(256) void flash_attn_k(
    const unsigned short* __restrict__ q, const unsigned short* __restrict__ k,
    const unsigned short* __restrict__ vt, unsigned short* __restrict__ o) {
  __shared__ unsigned short Ks[2][64 * 128];
  __shared__ unsigned short Vs[2][128 * 64];
  __shared__ unsigned short Ps[4 * 16 * 72];

  int L = blockIdx.x;
  int xcd = L & 7, j = L >> 3;
  int h = 2 * xcd + (j & 1);
  int qt = (j < 32) ? (31 - (j >> 1)) : ((j - 32) >> 1);

  int t = threadIdx.x, wave = t >> 6, lane = t & 63;
  int g = lane >> 4, li = lane & 15;
  int q0 = qt * 64;

  const unsigned short* vth = vt + (size_t)h * HDIM * S_LEN;

  auto stage = [&](int buf, int kt) {
    int kv0 = kt * 64;
#pragma unroll
    for (int i = 0; i < 4; ++i) {
      int ch = i * 256 + t;
      int row = ch >> 4, c = ch & 15;
      int cs_ = c ^ (row & 7);
      gload_lds16(k + (size_t)(kv0 + row) * DMODEL + h * HDIM + cs_ * 8,
                  &Ks[buf][ch * 8]);
    }
#pragma unroll
    for (int i = 0; i < 4; ++i) {
      int ch = i * 256 + t;
      int row = ch >> 3, c = ch & 7;
      int cs_ = c ^ (row & 7);
      gload_lds16(vth + (size_t)row * S_LEN + kv0 + cs_ * 8,
                  &Vs[buf][ch * 8]);
    }
  };

  int qrow = q0 + wave * 16 + li;
  bf16x8 qf[4];
#pragma unroll
  for (int kb = 0; kb < 4; ++kb)
    qf[kb] = *reinterpret_cast<const bf16x8*>(
        q + (size_t)qrow * DMODEL + h * HDIM + kb * 32 + g * 8);

  bf16x8 ones;
#pragma unroll
  for (int jj = 0; jj < 8; ++jj) ones[jj] = (__bf16)1.0f;

  f32x4 O[8];
#pragma unroll
  for (int db = 0; db < 8; ++db) O[db] = (f32x4){0.f, 0.f, 0.f, 0.f};
  f32x4 lA = (f32x4){0.f, 0.f, 0.f, 0.f};
  float m_r[4];
#pragma unroll
  for (int r = 0; r < 4; ++r) m_r[r] = -1e30f;

  // tile body; diag is a compile-time constant at each call site (inlined)
  auto tile_body = [&](int it, int cur, bool diag) {
    int kv0 = it * 64;
    // S = Q K^T  (log2-domain: q pre-scaled by sm*log2e)
    f32x4 sf[4];
#pragma unroll
    for (int jb = 0; jb < 4; ++jb) sf[jb] = (f32x4){0.f, 0.f, 0.f, 0.f};
#pragma unroll
    for (int kb = 0; kb < 4; ++kb) {
#pragma unroll
      for (int jb = 0; jb < 4; ++jb) {
        int row = jb * 16 + li;
        int c = (kb * 4 + g) ^ (row & 7);
        bf16x8 kf = *reinterpret_cast<const bf16x8*>(&Ks[cur][row * 128 + c * 8]);
        sf[jb] = __builtin_amdgcn_mfma_f32_16x16x32_bf16(qf[kb], kf, sf[jb], 0, 0, 0);
      }
    }

    float pm[4] = {-1e30f, -1e30f, -1e30f, -1e30f};
    if (diag) {
#pragma unroll
      for (int jb = 0; jb < 4; ++jb) {
        int jcol = kv0 + jb * 16 + li;
#pragma unroll
        for (int r = 0; r < 4; ++r) {
          int irow = q0 + wave * 16 + g * 4 + r;
          if (jcol > irow) sf[jb][r] = -1e30f;
          pm[r] = fmaxf(pm[r], sf[jb][r]);
        }
      }
    } else {
#pragma unroll
      for (int jb = 0; jb < 4; ++jb)
#pragma unroll
        for (int r = 0; r < 4; ++r) pm[r] = fmaxf(pm[r], sf[jb][r]);
    }
#pragma unroll
    for (int r = 0; r < 4; ++r) {
      float x = pm[r];
      x = fmaxf(x, __shfl_xor(x, 1));
      x = fmaxf(x, __shfl_xor(x, 2));
      x = fmaxf(x, __shfl_xor(x, 4));
      x = fmaxf(x, __shfl_xor(x, 8));
      pm[r] = x;
    }
    float alpha[4];
#pragma unroll
    for (int r = 0; r < 4; ++r) {
      float nm = fmaxf(m_r[r], pm[r]);
      alpha[r] = exp2f(m_r[r] - nm);
      m_r[r] = nm;
    }
    // P = exp2(S - m) -> per-wave LDS (A-operand layout roundtrip)
#pragma unroll
    for (int jb = 0; jb < 4; ++jb)
#pragma unroll
      for (int r = 0; r < 4; ++r)
        Ps[wave * 16 * 72 + (g * 4 + r) * 72 + jb * 16 + li] =
            f2b(exp2f(sf[jb][r] - m_r[r]));
    // rescale O and l
#pragma unroll
    for (int db = 0; db < 8; ++db)
#pragma unroll
      for (int r = 0; r < 4; ++r) O[db][r] *= alpha[r];
#pragma unroll
    for (int r = 0; r < 4; ++r) lA[r] *= alpha[r];

    // O += P V ; l += P . 1  (ones-MFMA)
#pragma unroll
    for (int ks = 0; ks < 2; ++ks) {
      bf16x8 pa = *reinterpret_cast<const bf16x8*>(
          Ps + wave * 16 * 72 + li * 72 + ks * 32 + g * 8);
      lA = __builtin_amdgcn_mfma_f32_16x16x32_bf16(pa, ones, lA, 0, 0, 0);
#pragma unroll
      for (int db = 0; db < 8; ++db) {
        int row = db * 16 + li;
        int c = (ks * 4 + g) ^ (row & 7);
        bf16x8 vbf = *reinterpret_cast<const bf16x8*>(&Vs[cur][row * 64 + c * 8]);
        O[db] = __builtin_amdgcn_mfma_f32_16x16x32_bf16(pa, vbf, O[db], 0, 0, 0);
      }
    }
  };

  stage(0, 0);

  for (int it = 0; it < qt; ++it) {
    int cur = it & 1;
    stage(cur ^ 1, it + 1);
    asm volatile("s_waitcnt vmcnt(8)" ::: "memory");
    __builtin_amdgcn_s_barrier();
    asm volatile("" ::: "memory");
    tile_body(it, cur, false);
    __builtin_amdgcn_s_barrier();
    asm volatile("" ::: "memory");
  }
  {
    int cur = qt & 1;
    asm volatile("s_waitcnt vmcnt(0)" ::: "memory");
    __builtin_amdgcn_s_barrier();
    asm volatile("" ::: "memory");
    tile_body(qt, cur, true);
  }

  // epilogue: O / l
#pragma unroll
  for (int db = 0; db < 8; ++db) {
#pragma unroll
    for (int r = 0; r < 4; ++r) {
      int row = q0 + wave * 16 + g * 4 + r;
      o[(size_t)row * DMODEL + h * HDIM + db * 16 + li] = f2b(O[db][r] / lA[r]);
    }
  }
}

extern "C" void kernel_launch(void* const* d_in, const int* in_sizes, int n_in,
                              void* d_out, int out_size, void* d_ws, size_t ws_size,
                              hipStream_t stream) {
  const float* hs = (const float*)d_in[0];
  const float* Wq = (const float*)d_in[1];
  const float* Wk = (const float*)d_in[2];
  const float* Wv = (const float*)d_in[3];
  const float* Wo = (const float*)d_in[4];

  char* ws = (char*)d_ws;
  const size_t MB = 1024 * 1024;
  unsigned short* hs_b = (unsigned short*)(ws + 0 * MB);  // reused as vt later
  unsigned short* Wq_b = (unsigned short*)(ws + 8 * MB);
  unsigned short* Wk_b = (unsigned short*)(ws + 16 * MB);
  unsigned short* Wv_b = (unsigned short*)(ws + 24 * MB);
  unsigned short* Wo_b = (unsigned short*)(ws + 32 * MB);
  unsigned short* qb = (unsigned short*)(ws + 40 * MB);
  unsigned short* kb = (unsigned short*)(ws + 48 * MB);
  unsigned short* vb = (unsigned short*)(ws + 56 * MB);
  unsigned short* ab = (unsigned short*)(ws + 64 * MB);
  float* cs = (float*)(ws + 72 * MB);
  float* sn = (float*)(ws + 72 * MB + 512 * 1024);
  unsigned short* vtb = hs_b;  // V^T [h][d][s]; hs_b dead after QKV GEMM

  cvt5_f32_bf16_k<<<(5 * 1024 * 1024) / 256, 256, 0, stream>>>(
      hs, Wq, Wk, Wv, Wo, hs_b, Wq_b, Wk_b, Wv_b, Wo_b);

  rope_table_k<<<(S_LEN * 64) / 256, 256, 0, stream>>>(cs, sn);

  gemm_8ph_k<256, false><<<dim3(64, 1, 3), 512, 0, stream>>>(
      hs_b, Wq_b, Wk_b, Wv_b, qb, kb, vb, 2048, 2048, 2048);

  transpose_bf16_k<<<dim3(32, 32), 256, 0, stream>>>(vb, vtb);

  rope_apply_k<<<(S_LEN * NHEADS * 64) / 256, 256, 0, stream>>>(qb, kb, cs, sn);

  flash_attn_k<<<dim3(512), 256, 0, stream>>>(qb, kb, vtb, ab);

  gemm_8ph_k<128, true><<<dim3(128, 1, 1), 512, 0, stream>>>(
      ab, Wo_b, Wo_b, Wo_b, d_out, d_out, d_out, 2048, 2048, 2048);
}

// Round 7
// 218.665 us; speedup vs baseline: 1.7286x; 1.0007x over previous
//
#include <hip/hip_runtime.h>
#include <hip/hip_bf16.h>
#include <math.h>

#define S_LEN 2048
#define DMODEL 2048
#define NHEADS 16
#define HDIM 128

typedef __bf16 bf16x8 __attribute__((ext_vector_type(8)));
typedef float f32x4 __attribute__((ext_vector_type(4)));

__device__ __forceinline__ unsigned short f2b(float f) {
  union { float f; unsigned u; } c; c.f = f;
  unsigned r = (c.u + 0x7fffu + ((c.u >> 16) & 1u)) >> 16;
  return (unsigned short)r;
}
__device__ __forceinline__ float b2f(unsigned short b) {
  union { unsigned u; float f; } c; c.u = ((unsigned)b) << 16;
  return c.f;
}

__device__ __forceinline__ void gload_lds16(const unsigned short* g, unsigned short* l) {
  __builtin_amdgcn_global_load_lds(
      (__attribute__((address_space(1))) void*)(void*)g,
      (__attribute__((address_space(3))) void*)(void*)l, 16, 0, 0);
}

// ---------------- fused fp32 -> bf16 conversion (5 tensors, one launch) ----
__global__ void cvt5_f32_bf16_k(const float* __restrict__ s0,
                                const float* __restrict__ s1,
                                const float* __restrict__ s2,
                                const float* __restrict__ s3,
                                const float* __restrict__ s4,
                                unsigned short* __restrict__ d0,
                                unsigned short* __restrict__ d1,
                                unsigned short* __restrict__ d2,
                                unsigned short* __restrict__ d3,
                                unsigned short* __restrict__ d4) {
  int gi = blockIdx.x * blockDim.x + threadIdx.x;
  int seg = gi >> 20;
  int i = (gi & 0xFFFFF) * 4;
  const float* src = (seg == 0) ? s0 : (seg == 1) ? s1 : (seg == 2) ? s2
                     : (seg == 3) ? s3 : s4;
  unsigned short* dst = (seg == 0) ? d0 : (seg == 1) ? d1 : (seg == 2) ? d2
                        : (seg == 3) ? d3 : d4;
  float4 v = *reinterpret_cast<const float4*>(src + i);
  ushort4 o;
  o.x = f2b(v.x); o.y = f2b(v.y); o.z = f2b(v.z); o.w = f2b(v.w);
  *reinterpret_cast<ushort4*>(dst + i) = o;
}

// ---------------- RoPE cos/sin table ----------------
__global__ void rope_table_k(float* __restrict__ cs, float* __restrict__ sn) {
  int idx = blockIdx.x * blockDim.x + threadIdx.x;  // S_LEN * 64
  int s = idx >> 6, i = idx & 63;
  float inv = powf(10000.0f, -(float)(2 * i) / 128.0f);
  float a = (float)s * inv;
  cs[idx] = cosf(a);
  sn[idx] = sinf(a);
}

// ---------------- RoPE apply (in-place on q,k bf16) ----------------
// q additionally scaled by sm*log2(e): softmax runs in log2 domain.
__global__ void rope_apply_k(unsigned short* __restrict__ q,
                             unsigned short* __restrict__ k,
                             const float* __restrict__ cs,
                             const float* __restrict__ sn) {
  const float SC = 0.08838834764831845f * 1.4426950408889634f;  // sm * log2e
  int idx = blockIdx.x * blockDim.x + threadIdx.x;  // S*H*64
  int i = idx & 63;
  int h = (idx >> 6) & (NHEADS - 1);
  int s = idx >> 10;
  size_t base = (size_t)s * DMODEL + h * HDIM;
  float c = cs[s * 64 + i], sv = sn[s * 64 + i];
  float qc = c * SC, qs = sv * SC;
  float q1 = b2f(q[base + i]), q2 = b2f(q[base + i + 64]);
  q[base + i]      = f2b(q1 * qc - q2 * qs);
  q[base + i + 64] = f2b(q2 * qc + q1 * qs);
  float k1 = b2f(k[base + i]), k2 = b2f(k[base + i + 64]);
  k[base + i]      = f2b(k1 * c - k2 * sv);
  k[base + i + 64] = f2b(k2 * c + k1 * sv);
}

// ---------------- bf16 2048x2048 transpose ----------------
__global__ __launch_bounds__(256) void transpose_bf16_k(
    const unsigned short* __restrict__ in, unsigned short* __restrict__ out) {
  __shared__ unsigned short tile[64][72];
  int bx = blockIdx.x, by = blockIdx.y;
  int t = threadIdx.x;
#pragma unroll
  for (int i = 0; i < 2; ++i) {
    int ch = i * 256 + t;
    int r = ch >> 3, c8 = ch & 7;
    bf16x8 v = *reinterpret_cast<const bf16x8*>(
        in + (size_t)(by * 64 + r) * DMODEL + bx * 64 + c8 * 8);
    *reinterpret_cast<bf16x8*>(&tile[r][c8 * 8]) = v;
  }
  __syncthreads();
#pragma unroll
  for (int i = 0; i < 2; ++i) {
    int ch = i * 256 + t;
    int c = ch >> 3, r8 = ch & 7;
    union { bf16x8 v; unsigned short u[8]; } w;
#pragma unroll
    for (int j = 0; j < 8; ++j) w.u[j] = tile[r8 * 8 + j][c];
    *reinterpret_cast<bf16x8*>(
        out + (size_t)(bx * 64 + c) * S_LEN + by * 64 + r8 * 8) = w.v;
  }
}

// ============ 8-phase 256-wide NT GEMM (unchanged, verified) ============

#define MIDBAR_SEQ()                                      \
  do {                                                    \
    asm volatile("" ::: "memory");                        \
    __builtin_amdgcn_s_barrier();                         \
    asm volatile("s_waitcnt lgkmcnt(0)" ::: "memory");    \
    __builtin_amdgcn_sched_barrier(0);                    \
    __builtin_amdgcn_s_setprio(1);                        \
  } while (0)

#define ENDBAR_SEQ()                                      \
  do {                                                    \
    __builtin_amdgcn_s_setprio(0);                        \
    asm volatile("" ::: "memory");                        \
    __builtin_amdgcn_s_barrier();                         \
    asm volatile("" ::: "memory");                        \
  } while (0)

#define READA(QM)                                                              \
  do {                                                                         \
    _Pragma("unroll") for (int j = 0; j < MQ; ++j)                             \
    _Pragma("unroll") for (int kk = 0; kk < 2; ++kk) {                         \
      int row = wm * (BM / 2) + ((QM) * MQ + j) * 16 + li;                     \
      int c = (kk * 4 + g) ^ (li & 7);                                         \
      af[j][kk] = *reinterpret_cast<const bf16x8*>(&As[cur][row * 64 + c * 8]);\
    }                                                                          \
  } while (0)

#define READB(BF, QN)                                                          \
  do {                                                                         \
    _Pragma("unroll") for (int jn = 0; jn < 2; ++jn)                           \
    _Pragma("unroll") for (int kk = 0; kk < 2; ++kk) {                         \
      int row = wn * 64 + ((QN) * 2 + jn) * 16 + li;                           \
      int c = (kk * 4 + g) ^ (li & 7);                                         \
      BF[jn][kk] = *reinterpret_cast<const bf16x8*>(&Bs[cur][row * 64 + c * 8]);\
    }                                                                          \
  } while (0)

#define QUAD(QM, QN, BF)                                                       \
  do {                                                                         \
    _Pragma("unroll") for (int j = 0; j < MQ; ++j)                             \
    _Pragma("unroll") for (int jn = 0; jn < 2; ++jn)                           \
    _Pragma("unroll") for (int kk = 0; kk < 2; ++kk)                           \
      acc[(QM) * MQ + j][(QN) * 2 + jn] =                                      \
          __builtin_amdgcn_mfma_f32_16x16x32_bf16(                             \
              af[j][kk], BF[jn][kk], acc[(QM) * MQ + j][(QN) * 2 + jn], 0, 0, 0);\
  } while (0)

template <int BM, bool OUT_F32>
__global__ __launch_bounds__(512, 2) void gemm_8ph_k(
    const unsigned short* __restrict__ A, const unsigned short* __restrict__ B0p,
    const unsigned short* __restrict__ B1p, const unsigned short* __restrict__ B2p,
    void* __restrict__ C0, void* __restrict__ C1, void* __restrict__ C2,
    int M, int N, int K) {
  constexpr int MQ = BM / 64;
  constexpr int MR = BM / 32;

  __shared__ unsigned short As[2][BM * 64];
  __shared__ unsigned short Bs[2][256 * 64];

  const unsigned short* Bp = (blockIdx.z == 0) ? B0p : (blockIdx.z == 1) ? B1p : B2p;
  void* Cout = (blockIdx.z == 0) ? C0 : (blockIdx.z == 1) ? C1 : C2;

  int nwg = gridDim.x, bid = blockIdx.x;
  int wg = (bid & 7) * (nwg >> 3) + (bid >> 3);
  int ntn = N >> 8;
  int tm = wg / ntn, tn = wg % ntn;
  int m0 = tm * BM, n0 = tn << 8;

  const int tid = threadIdx.x;
  const int wave = tid >> 6, lane = tid & 63;
  const int g = lane >> 4, li = lane & 15;
  const int wm = wave >> 2, wn = wave & 3;

  auto stageB = [&](int buf, int tt, int qn) {
#pragma unroll
    for (int i = 0; i < 2; ++i) {
      int j = i * 512 + tid;
      int piece = j >> 8, rowin = (j >> 3) & 31, c = j & 7;
      int row = piece * 64 + qn * 32 + rowin;
      gload_lds16(Bp + (size_t)(n0 + row) * K + tt * 64 + ((c ^ (row & 7)) * 8),
                  &Bs[buf][row * 64 + c * 8]);
    }
  };
  auto stageA = [&](int buf, int tt, int qm) {
#pragma unroll
    for (int i = 0; i < BM / 128; ++i) {
      int j = i * 512 + tid;
      int piece = j / (2 * BM);
      int rowin = (j >> 3) & (BM / 4 - 1);
      int c = j & 7;
      int row = piece * (BM / 2) + qm * (BM / 4) + rowin;
      gload_lds16(A + (size_t)(m0 + row) * K + tt * 64 + ((c ^ (row & 7)) * 8),
                  &As[buf][row * 64 + c * 8]);
    }
  };

  f32x4 acc[MR][4];
#pragma unroll
  for (int i = 0; i < MR; ++i)
#pragma unroll
    for (int j = 0; j < 4; ++j) acc[i][j] = (f32x4){0.f, 0.f, 0.f, 0.f};

  const int nK = K >> 6;

  stageB(0, 0, 0); stageA(0, 0, 0); stageB(0, 0, 1); stageA(0, 0, 1);
  stageB(1, 1, 0); stageA(1, 1, 0); stageB(1, 1, 1); stageA(1, 1, 1);
  if constexpr (BM == 256) asm volatile("s_waitcnt vmcnt(8)" ::: "memory");
  else                     asm volatile("s_waitcnt vmcnt(6)" ::: "memory");
  asm volatile("" ::: "memory");
  __builtin_amdgcn_s_barrier();
  asm volatile("" ::: "memory");

  for (int t = 0; t < nK; ++t) {
    int cur = t & 1;
    bool pf = (t + 2 < nK);
    bf16x8 af[MQ][2], bf0[2][2], bf1[2][2];
    READA(0);
    READB(bf0, 0);
    MIDBAR_SEQ();
    QUAD(0, 0, bf0);
    ENDBAR_SEQ();
    READB(bf1, 1);
    if (pf) { stageB(cur, t + 2, 0); stageA(cur, t + 2, 0); }
    MIDBAR_SEQ();
    QUAD(0, 1, bf1);
    ENDBAR_SEQ();
    READA(1);
    if (pf) stageB(cur, t + 2, 1);
    MIDBAR_SEQ();
    QUAD(1, 1, bf1);
    ENDBAR_SEQ();
    if (pf) {
      stageA(cur, t + 2, 1);
      if constexpr (BM == 256) asm volatile("s_waitcnt vmcnt(8)" ::: "memory");
      else                     asm volatile("s_waitcnt vmcnt(6)" ::: "memory");
    } else {
      asm volatile("s_waitcnt vmcnt(0)" ::: "memory");
    }
    MIDBAR_SEQ();
    QUAD(1, 0, bf0);
    ENDBAR_SEQ();
  }

#pragma unroll
  for (int m = 0; m < MR; ++m) {
#pragma unroll
    for (int n = 0; n < 4; ++n) {
      int row = m0 + wm * (BM / 2) + m * 16 + g * 4;
      int col = n0 + wn * 64 + n * 16 + li;
#pragma unroll
      for (int r = 0; r < 4; ++r) {
        if (OUT_F32)
          reinterpret_cast<float*>(Cout)[(size_t)(row + r) * N + col] = acc[m][n][r];
        else
          reinterpret_cast<unsigned short*>(Cout)[(size_t)(row + r) * N + col] =
              f2b(acc[m][n][r]);
      }
    }
  }
}

#undef MIDBAR_SEQ
#undef ENDBAR_SEQ
#undef READA
#undef READB
#undef QUAD

// ---------------- causal flash attention v4 ----------------
// 512 blocks, 4 waves, LDS 57 KB (<64 KB) so 2 blocks/CU co-reside.
// K double-buffered; V single-buffered with WAR-safe schedule:
//   stage V(it) [safe: B2(it-1)] ; stage K(it+1)->Ks[!cur] ;
//   QK(it) [K(it) landed: vmcnt(0)+B1 of it-1] ; softmax->Ps (per-wave) ;
//   vmcnt(0) ; B1 [all waves' V(it)+K(it+1) landed] ; PV(it) ; B2.
// 2-heads-per-XCD locality + LPT pairing (proven rounds 5/6) retained.
__global__ __launch_bounds__(256) void flash_attn_k(
    const unsigned short* __restrict__ q, const unsigned short* __restrict__ k,
    const unsigned short* __restrict__ vt, unsigned short* __restrict__ o) {
  __shared__ unsigned short Ks[2][64 * 128];  // 32 KB, chunk ^= row&7
  __shared__ unsigned short Vs[128 * 64];     // 16 KB, chunk ^= row&7
  __shared__ unsigned short Ps[4 * 16 * 72];  // 9 KB per-wave P roundtrip

  int L = blockIdx.x;
  int xcd = L & 7, j = L >> 3;
  int h = 2 * xcd + (j & 1);
  int qt = (j < 32) ? (31 - (j >> 1)) : ((j - 32) >> 1);

  int t = threadIdx.x, wave = t >> 6, lane = t & 63;
  int g = lane >> 4, li = lane & 15;
  int q0 = qt * 64;

  const unsigned short* vth = vt + (size_t)h * HDIM * S_LEN;

  auto stageK = [&](int buf, int kt) {
    int kv0 = kt * 64;
#pragma unroll
    for (int i = 0; i < 4; ++i) {
      int ch = i * 256 + t;
      int row = ch >> 4, c = ch & 15;
      int cs_ = c ^ (row & 7);
      gload_lds16(k + (size_t)(kv0 + row) * DMODEL + h * HDIM + cs_ * 8,
                  &Ks[buf][ch * 8]);
    }
  };
  auto stageV = [&](int kt) {
    int kv0 = kt * 64;
#pragma unroll
    for (int i = 0; i < 4; ++i) {
      int ch = i * 256 + t;
      int row = ch >> 3, c = ch & 7;
      int cs_ = c ^ (row & 7);
      gload_lds16(vth + (size_t)row * S_LEN + kv0 + cs_ * 8, &Vs[ch * 8]);
    }
  };

  int qrow = q0 + wave * 16 + li;
  bf16x8 qf[4];
#pragma unroll
  for (int kb = 0; kb < 4; ++kb)
    qf[kb] = *reinterpret_cast<const bf16x8*>(
        q + (size_t)qrow * DMODEL + h * HDIM + kb * 32 + g * 8);

  bf16x8 ones;
#pragma unroll
  for (int jj = 0; jj < 8; ++jj) ones[jj] = (__bf16)1.0f;

  f32x4 O[8];
#pragma unroll
  for (int db = 0; db < 8; ++db) O[db] = (f32x4){0.f, 0.f, 0.f, 0.f};
  f32x4 lA = (f32x4){0.f, 0.f, 0.f, 0.f};
  float m_r[4];
#pragma unroll
  for (int r = 0; r < 4; ++r) m_r[r] = -1e30f;

  // prologue: K(0) must be visible to all waves before QK(0)
  stageK(0, 0);
  asm volatile("s_waitcnt vmcnt(0)" ::: "memory");
  __builtin_amdgcn_s_barrier();
  asm volatile("" ::: "memory");

  for (int it = 0; it <= qt; ++it) {
    int cur = it & 1;
    bool diag = (it == qt);
    int kv0 = it * 64;

    stageV(it);                          // WAR-safe: B2(it-1) / prologue barrier
    if (!diag) stageK(cur ^ 1, it + 1);  // WAR-safe: Ks[!cur] last read in it-1

    // S = Q K^T (log2 domain; q pre-scaled by sm*log2e)
    f32x4 sf[4];
#pragma unroll
    for (int jb = 0; jb < 4; ++jb) sf[jb] = (f32x4){0.f, 0.f, 0.f, 0.f};
#pragma unroll
    for (int kb = 0; kb < 4; ++kb) {
#pragma unroll
      for (int jb = 0; jb < 4; ++jb) {
        int row = jb * 16 + li;
        int c = (kb * 4 + g) ^ (row & 7);
        bf16x8 kf = *reinterpret_cast<const bf16x8*>(&Ks[cur][row * 128 + c * 8]);
        sf[jb] = __builtin_amdgcn_mfma_f32_16x16x32_bf16(qf[kb], kf, sf[jb], 0, 0, 0);
      }
    }

    float pm[4] = {-1e30f, -1e30f, -1e30f, -1e30f};
    if (diag) {
#pragma unroll
      for (int jb = 0; jb < 4; ++jb) {
        int jcol = kv0 + jb * 16 + li;
#pragma unroll
        for (int r = 0; r < 4; ++r) {
          int irow = q0 + wave * 16 + g * 4 + r;
          if (jcol > irow) sf[jb][r] = -1e30f;
          pm[r] = fmaxf(pm[r], sf[jb][r]);
        }
      }
    } else {
#pragma unroll
      for (int jb = 0; jb < 4; ++jb)
#pragma unroll
        for (int r = 0; r < 4; ++r) pm[r] = fmaxf(pm[r], sf[jb][r]);
    }
#pragma unroll
    for (int r = 0; r < 4; ++r) {
      float x = pm[r];
      x = fmaxf(x, __shfl_xor(x, 1));
      x = fmaxf(x, __shfl_xor(x, 2));
      x = fmaxf(x, __shfl_xor(x, 4));
      x = fmaxf(x, __shfl_xor(x, 8));
      pm[r] = x;
    }
    float alpha[4];
#pragma unroll
    for (int r = 0; r < 4; ++r) {
      float nm = fmaxf(m_r[r], pm[r]);
      alpha[r] = exp2f(m_r[r] - nm);
      m_r[r] = nm;
    }
    // P = exp2(S - m) -> per-wave LDS (A-operand layout roundtrip)
#pragma unroll
    for (int jb = 0; jb < 4; ++jb)
#pragma unroll
      for (int r = 0; r < 4; ++r)
        Ps[wave * 16 * 72 + (g * 4 + r) * 72 + jb * 16 + li] =
            f2b(exp2f(sf[jb][r] - m_r[r]));
    // rescale O and l
#pragma unroll
    for (int db = 0; db < 8; ++db)
#pragma unroll
      for (int r = 0; r < 4; ++r) O[db][r] *= alpha[r];
#pragma unroll
    for (int r = 0; r < 4; ++r) lA[r] *= alpha[r];

    // B1: all waves' V(it) (+K(it+1)) landed
    asm volatile("s_waitcnt vmcnt(0)" ::: "memory");
    __builtin_amdgcn_s_barrier();
    asm volatile("" ::: "memory");

    // O += P V ; l += P . 1
#pragma unroll
    for (int ks = 0; ks < 2; ++ks) {
      bf16x8 pa = *reinterpret_cast<const bf16x8*>(
          Ps + wave * 16 * 72 + li * 72 + ks * 32 + g * 8);
      lA = __builtin_amdgcn_mfma_f32_16x16x32_bf16(pa, ones, lA, 0, 0, 0);
#pragma unroll
      for (int db = 0; db < 8; ++db) {
        int row = db * 16 + li;
        int c = (ks * 4 + g) ^ (row & 7);
        bf16x8 vbf = *reinterpret_cast<const bf16x8*>(&Vs[row * 64 + c * 8]);
        O[db] = __builtin_amdgcn_mfma_f32_16x16x32_bf16(pa, vbf, O[db], 0, 0, 0);
      }
    }

    if (!diag) {  // B2: everyone done reading Vs before next stageV
      __builtin_amdgcn_s_barrier();
      asm volatile("" ::: "memory");
    }
  }

  // epilogue: O / l
#pragma unroll
  for (int db = 0; db < 8; ++db) {
#pragma unroll
    for (int r = 0; r < 4; ++r) {
      int row = q0 + wave * 16 + g * 4 + r;
      o[(size_t)row * DMODEL + h * HDIM + db * 16 + li] = f2b(O[db][r] / lA[r]);
    }
  }
}

extern "C" void kernel_launch(void* const* d_in, const int* in_sizes, int n_in,
                              void* d_out, int out_size, void* d_ws, size_t ws_size,
                              hipStream_t stream) {
  const float* hs = (const float*)d_in[0];
  const float* Wq = (const float*)d_in[1];
  const float* Wk = (const float*)d_in[2];
  const float* Wv = (const float*)d_in[3];
  const float* Wo = (const float*)d_in[4];

  char* ws = (char*)d_ws;
  const size_t MB = 1024 * 1024;
  unsigned short* hs_b = (unsigned short*)(ws + 0 * MB);  // reused as vt later
  unsigned short* Wq_b = (unsigned short*)(ws + 8 * MB);
  unsigned short* Wk_b = (unsigned short*)(ws + 16 * MB);
  unsigned short* Wv_b = (unsigned short*)(ws + 24 * MB);
  unsigned short* Wo_b = (unsigned short*)(ws + 32 * MB);
  unsigned short* qb = (unsigned short*)(ws + 40 * MB);
  unsigned short* kb = (unsigned short*)(ws + 48 * MB);
  unsigned short* vb = (unsigned short*)(ws + 56 * MB);
  unsigned short* ab = (unsigned short*)(ws + 64 * MB);
  float* cs = (float*)(ws + 72 * MB);
  float* sn = (float*)(ws + 72 * MB + 512 * 1024);
  unsigned short* vtb = hs_b;  // V^T [h][d][s]; hs_b dead after QKV GEMM

  cvt5_f32_bf16_k<<<(5 * 1024 * 1024) / 256, 256, 0, stream>>>(
      hs, Wq, Wk, Wv, Wo, hs_b, Wq_b, Wk_b, Wv_b, Wo_b);

  rope_table_k<<<(S_LEN * 64) / 256, 256, 0, stream>>>(cs, sn);

  gemm_8ph_k<256, false><<<dim3(64, 1, 3), 512, 0, stream>>>(
      hs_b, Wq_b, Wk_b, Wv_b, qb, kb, vb, 2048, 2048, 2048);

  transpose_bf16_k<<<dim3(32, 32), 256, 0, stream>>>(vb, vtb);

  rope_apply_k<<<(S_LEN * NHEADS * 64) / 256, 256, 0, stream>>>(qb, kb, cs, sn);

  flash_attn_k<<<dim3(512), 256, 0, stream>>>(qb, kb, vtb, ab);

  gemm_8ph_k<128, true><<<dim3(128, 1, 1), 512, 0, stream>>>(
      ab, Wo_b, Wo_b, Wo_b, d_out, d_out, d_out, 2048, 2048, 2048);
}